// Round 6
// baseline (1961.559 us; speedup 1.0000x reference)
//
#include <hip/hip_runtime.h>

// ---------------------------------------------------------------------------
// Recurrent GraphSAGE net. Round 6: XCD channel-sliced gather.
//  - Activations (h1,h2,aggb) stored as 4 panels of N x 32 bf16 (3.2MB each,
//    fits one XCD's 4MiB L2). agg grid: blockIdx%8 -> XCD -> slice (2 XCDs
//    per slice); each XCD's gather reads stay in its local L2.
//  - Activation writes + col reads are nontemporal (don't evict the panel).
//  - Separate agg + MFMA gemm kernels (R5 fusion regressed: gather is
//    TLP-bound, needs the full 800K-thread grid).
// Per timestep: enc1, [agg, gemm] x2, [agg, gemm+head] = 7 dispatches.
// ---------------------------------------------------------------------------

typedef __attribute__((ext_vector_type(8))) short short8;
typedef __attribute__((ext_vector_type(8))) unsigned short ushort8;
typedef __attribute__((ext_vector_type(4))) float f32x4;

static __device__ __forceinline__ float b2f(unsigned short u) {
  return __uint_as_float(((unsigned int)u) << 16);
}
static __device__ __forceinline__ unsigned short f2bf(float f) {
  unsigned int u = __float_as_uint(f);
  u += 0x7FFFu + ((u >> 16) & 1u);   // round-nearest-even
  return (unsigned short)(u >> 16);
}

// ---------------- graph preprocessing ----------------

__global__ void count_rank_kernel(const int* __restrict__ dst, int* __restrict__ cnt,
                                  int* __restrict__ rank, int E) {
  int e = blockIdx.x * blockDim.x + threadIdx.x;
  if (e < E) rank[e] = atomicAdd(&cnt[dst[e]], 1);
}

__global__ __launch_bounds__(256) void blocksum_kernel(const int* __restrict__ cnt,
                                                       int* __restrict__ bsum, int n) {
  __shared__ int s[256];
  int tid = threadIdx.x;
  int i = blockIdx.x * 256 + tid;
  s[tid] = (i < n) ? cnt[i] : 0;
  __syncthreads();
  for (int off = 128; off > 0; off >>= 1) {
    if (tid < off) s[tid] += s[tid + off];
    __syncthreads();
  }
  if (tid == 0) bsum[blockIdx.x] = s[0];
}

__global__ __launch_bounds__(256) void scan_sums_kernel(const int* __restrict__ bsum,
                                                        int* __restrict__ boff, int nb) {
  __shared__ int s[256];
  int tid = threadIdx.x;
  int v = (tid < nb) ? bsum[tid] : 0;
  s[tid] = v;
  __syncthreads();
  for (int off = 1; off < 256; off <<= 1) {
    int t = (tid >= off) ? s[tid - off] : 0;
    __syncthreads();
    s[tid] += t;
    __syncthreads();
  }
  if (tid < nb) boff[tid] = s[tid] - v;   // exclusive
}

__global__ __launch_bounds__(256) void expand_kernel(const int* __restrict__ cnt,
                                                     const int* __restrict__ boff,
                                                     int* __restrict__ row_ptr,
                                                     float* __restrict__ rdeg, int n) {
  __shared__ int s[256];
  int tid = threadIdx.x;
  int i = blockIdx.x * 256 + tid;
  int v = (i < n) ? cnt[i] : 0;
  s[tid] = v;
  __syncthreads();
  for (int off = 1; off < 256; off <<= 1) {
    int t = (tid >= off) ? s[tid - off] : 0;
    __syncthreads();
    s[tid] += t;
    __syncthreads();
  }
  if (i < n) {
    row_ptr[i + 1] = boff[blockIdx.x] + s[tid];
    rdeg[i] = 1.0f / fmaxf((float)v, 1.0f);
  }
  if (i == 0) row_ptr[0] = 0;
}

__global__ void fill_csr2_kernel(const int* __restrict__ src, const int* __restrict__ dst,
                                 const int* __restrict__ rank, const int* __restrict__ row_ptr,
                                 int* __restrict__ col, int E) {
  int e = blockIdx.x * blockDim.x + threadIdx.x;
  if (e < E) col[row_ptr[dst[e]] + rank[e]] = src[e];
}

__global__ void f2bf6_kernel(const float* __restrict__ s0, const float* __restrict__ s1,
                             const float* __restrict__ s2, const float* __restrict__ s3,
                             const float* __restrict__ s4, const float* __restrict__ s5,
                             unsigned short* __restrict__ dst) {
  int i = blockIdx.x * blockDim.x + threadIdx.x;
  if (i >= 6 * 16384) return;
  int m = i >> 14, o = i & 16383;
  const float* s;
  switch (m) {
    case 0: s = s0; break; case 1: s = s1; break; case 2: s = s2; break;
    case 3: s = s3; break; case 4: s = s4; break; default: s = s5; break;
  }
  dst[i] = f2bf(s[o]);
}

// mean-aggregate mesh (8 fp32 ch): 2 lanes/node, once per launch
__global__ void aggmesh_kernel(const float* __restrict__ mesh, float* __restrict__ aggm,
                               const int* __restrict__ row_ptr, const int* __restrict__ col,
                               const float* __restrict__ rdeg, int N) {
  int g = blockIdx.x * blockDim.x + threadIdx.x;
  int node = g >> 1, h = (g & 1) * 4;
  if (node >= N) return;
  int j0 = row_ptr[node], j1 = row_ptr[node + 1];
  float4 acc = make_float4(0.f, 0.f, 0.f, 0.f);
  int j = j0;
  for (; j + 4 <= j1; j += 4) {
    float4 v0 = *(const float4*)&mesh[col[j] * 8 + h];
    float4 v1 = *(const float4*)&mesh[col[j + 1] * 8 + h];
    float4 v2 = *(const float4*)&mesh[col[j + 2] * 8 + h];
    float4 v3 = *(const float4*)&mesh[col[j + 3] * 8 + h];
    acc.x += (v0.x + v1.x) + (v2.x + v3.x);
    acc.y += (v0.y + v1.y) + (v2.y + v3.y);
    acc.z += (v0.z + v1.z) + (v2.z + v3.z);
    acc.w += (v0.w + v1.w) + (v2.w + v3.w);
  }
  for (; j < j1; ++j) {
    float4 v0 = *(const float4*)&mesh[col[j] * 8 + h];
    acc.x += v0.x; acc.y += v0.y; acc.z += v0.z; acc.w += v0.w;
  }
  float r = rdeg[node];
  acc.x *= r; acc.y *= r; acc.z *= r; acc.w *= r;
  *(float4*)&aggm[node * 8 + h] = acc;
}

// mterm[n][o] = bl[o] + sum_k Wl[o][4+k]*aggm[n][k] + Wr[o][4+k]*mesh[n][k]
__global__ void mesh_term_kernel(const float* __restrict__ aggm, const float* __restrict__ mesh,
                                 const float* __restrict__ Wl, const float* __restrict__ Wr,
                                 const float* __restrict__ bl, unsigned short* __restrict__ mterm,
                                 int N) {
  int g = blockIdx.x * blockDim.x + threadIdx.x;
  if (g >= N * 128) return;
  int n = g >> 7, o = g & 127;
  float acc = bl[o];
#pragma unroll
  for (int k = 0; k < 8; ++k)
    acc += Wl[o * 12 + 4 + k] * aggm[n * 8 + k] + Wr[o * 12 + 4 + k] * mesh[n * 8 + k];
  mterm[g] = f2bf(acc);
}

// ---------------- per-timestep kernels ----------------

// enc1: gather xprev (float4 rows), K=8 GEMM, + mterm, relu -> bf16 panels.
__global__ __launch_bounds__(256) void enc1_kernel(
    const float* __restrict__ xprev, const int* __restrict__ row_ptr,
    const int* __restrict__ col, const float* __restrict__ rdeg,
    const float* __restrict__ Wl, const float* __restrict__ Wr,
    const unsigned short* __restrict__ mterm, unsigned short* __restrict__ out, int N) {
  __shared__ float Wx[8][128];   // k<4: Wl[:, k]; k>=4: Wr[:, k-4]
  __shared__ float4 part[256];
  __shared__ float As[64][8];    // [node][aggx(4) | own(4)]
  size_t N32 = (size_t)N * 32;
  int tid = threadIdx.x;
  int nb = blockIdx.x * 64;
  for (int i = tid; i < 1024; i += 256) {
    int k = i >> 7, o = i & 127;
    Wx[k][o] = (k < 4) ? Wl[o * 12 + k] : Wr[o * 12 + (k - 4)];
  }
  int nl = tid >> 2, q = tid & 3;
  int gn = nb + nl; if (gn > N - 1) gn = N - 1;
  int j0 = row_ptr[gn], j1 = row_ptr[gn + 1];
  int per = (j1 - j0 + 3) >> 2;
  int a = j0 + q * per; if (a > j1) a = j1;
  int b = a + per; if (b > j1) b = j1;
  float4 acc = make_float4(0.f, 0.f, 0.f, 0.f);
  int j = a;
  for (; j + 2 <= b; j += 2) {
    int s0 = __builtin_nontemporal_load(&col[j]);
    int s1 = __builtin_nontemporal_load(&col[j + 1]);
    float4 v0 = *(const float4*)&xprev[s0 * 4];
    float4 v1 = *(const float4*)&xprev[s1 * 4];
    acc.x += v0.x + v1.x; acc.y += v0.y + v1.y;
    acc.z += v0.z + v1.z; acc.w += v0.w + v1.w;
  }
  if (j < b) {
    float4 v0 = *(const float4*)&xprev[__builtin_nontemporal_load(&col[j]) * 4];
    acc.x += v0.x; acc.y += v0.y; acc.z += v0.z; acc.w += v0.w;
  }
  part[tid] = acc;
  __syncthreads();
  if (tid < 64) {
    int g2 = nb + tid; if (g2 > N - 1) g2 = N - 1;
    float4 s0 = part[tid * 4], s1 = part[tid * 4 + 1];
    float4 s2 = part[tid * 4 + 2], s3 = part[tid * 4 + 3];
    float r = rdeg[g2];
    As[tid][0] = (s0.x + s1.x + s2.x + s3.x) * r;
    As[tid][1] = (s0.y + s1.y + s2.y + s3.y) * r;
    As[tid][2] = (s0.z + s1.z + s2.z + s3.z) * r;
    As[tid][3] = (s0.w + s1.w + s2.w + s3.w) * r;
    float4 own = *(const float4*)&xprev[g2 * 4];
    As[tid][4] = own.x; As[tid][5] = own.y; As[tid][6] = own.z; As[tid][7] = own.w;
  }
  __syncthreads();
  int gn2 = nb + nl;
  if (gn2 >= N) return;
  float av[8];
#pragma unroll
  for (int k = 0; k < 8; ++k) av[k] = As[nl][k];
  int o0 = q * 32;
  unsigned short* op = out + (size_t)q * N32 + (size_t)gn2 * 32;  // panel q
#pragma unroll
  for (int c = 0; c < 4; ++c) {
    ushort8 mt = *(const ushort8*)&mterm[gn2 * 128 + o0 + c * 8];
    ushort8 ov;
#pragma unroll
    for (int oo = 0; oo < 8; ++oo) {
      int o = o0 + c * 8 + oo;
      float s = b2f(mt[oo]);
#pragma unroll
      for (int k = 0; k < 8; ++k) s += av[k] * Wx[k][o];
      ov[oo] = f2bf(fmaxf(s, 0.0f));
    }
    __builtin_nontemporal_store(ov, (ushort8*)&op[c * 8]);
  }
}

// XCD-sliced bf16 mean-aggregate over panels.
// blockIdx%8 = XCD; slice = xcd>>1 (2 XCDs per 32-ch panel, 3.2MB L2-resident).
// 4 lanes/node x 8 ch (16B); 64 nodes/block; nt col loads + nt output stores.
__global__ __launch_bounds__(256) void agg128_sliced_kernel(
    const unsigned short* __restrict__ feat, unsigned short* __restrict__ out,
    const int* __restrict__ row_ptr, const int* __restrict__ col,
    const float* __restrict__ rdeg, int N) {
  int b = blockIdx.x;
  int xcd = b & 7;
  int slice = xcd >> 1;
  int chunk = (b >> 3) * 2 + (xcd & 1);
  int node = chunk * 64 + (threadIdx.x >> 2);
  if (node >= N) return;
  int d = threadIdx.x & 3;
  size_t N32 = (size_t)N * 32;
  const unsigned short* fp = feat + (size_t)slice * N32 + d * 8;
  int j0 = row_ptr[node], j1 = row_ptr[node + 1];
  float acc[8] = {};
  int j = j0;
  for (; j + 4 <= j1; j += 4) {
    int s0 = __builtin_nontemporal_load(&col[j]);
    int s1 = __builtin_nontemporal_load(&col[j + 1]);
    int s2 = __builtin_nontemporal_load(&col[j + 2]);
    int s3 = __builtin_nontemporal_load(&col[j + 3]);
    ushort8 v0 = *(const ushort8*)&fp[(size_t)s0 * 32];
    ushort8 v1 = *(const ushort8*)&fp[(size_t)s1 * 32];
    ushort8 v2 = *(const ushort8*)&fp[(size_t)s2 * 32];
    ushort8 v3 = *(const ushort8*)&fp[(size_t)s3 * 32];
#pragma unroll
    for (int r = 0; r < 8; ++r)
      acc[r] += (b2f(v0[r]) + b2f(v1[r])) + (b2f(v2[r]) + b2f(v3[r]));
  }
  for (; j < j1; ++j) {
    int s0 = __builtin_nontemporal_load(&col[j]);
    ushort8 v0 = *(const ushort8*)&fp[(size_t)s0 * 32];
#pragma unroll
    for (int r = 0; r < 8; ++r) acc[r] += b2f(v0[r]);
  }
  float rd = rdeg[node];
  ushort8 o;
#pragma unroll
  for (int r = 0; r < 8; ++r) o[r] = f2bf(acc[r] * rd);
  __builtin_nontemporal_store(
      o, (ushort8*)&out[(size_t)slice * N32 + (size_t)node * 32 + d * 8]);
}

// conv GEMM via MFMA over panels: out = relu([agg|x] @ [Wl;Wr]^T + bl)
__global__ __launch_bounds__(256) void gemm128_mfma_kernel(
    const unsigned short* __restrict__ agg, const unsigned short* __restrict__ x,
    const unsigned short* __restrict__ Wlb, const unsigned short* __restrict__ Wrb,
    const float* __restrict__ bl, unsigned short* __restrict__ out, int N) {
  size_t N32 = (size_t)N * 32;
  int tid = threadIdx.x;
  int wave = tid >> 6;
  int lane = tid & 63;
  int nb = blockIdx.x * 128 + wave * 32;
  int l15 = lane & 15;
  int lk = (lane >> 4) * 8;

  f32x4 acc[2][8] = {};
  int r0 = nb + l15;      if (r0 > N - 1) r0 = N - 1;
  int r1 = nb + 16 + l15; if (r1 > N - 1) r1 = N - 1;

#pragma unroll
  for (int ks = 0; ks < 8; ++ks) {
    const unsigned short* P = (ks < 4) ? (agg + (size_t)ks * N32)
                                       : (x + (size_t)(ks - 4) * N32);
    short8 a0 = *(const short8*)&P[(size_t)r0 * 32 + lk];
    short8 a1 = *(const short8*)&P[(size_t)r1 * 32 + lk];
    const unsigned short* Ws = (ks < 4) ? Wlb : Wrb;
    int ko = (ks & 3) * 32 + lk;
#pragma unroll
    for (int ot = 0; ot < 8; ++ot) {
      short8 b = *(const short8*)&Ws[(ot * 16 + l15) * 128 + ko];
      acc[0][ot] = __builtin_amdgcn_mfma_f32_16x16x32_bf16(a0, b, acc[0][ot], 0, 0, 0);
      acc[1][ot] = __builtin_amdgcn_mfma_f32_16x16x32_bf16(a1, b, acc[1][ot], 0, 0, 0);
    }
  }

  int crow = (lane >> 4) * 4;   // C: col = lane&15, row = (lane>>4)*4 + reg
#pragma unroll
  for (int ot = 0; ot < 8; ++ot) {
    int gcol = ot * 16 + l15;
    float bv = bl[gcol];
    unsigned short* op = out + (size_t)(gcol >> 5) * N32 + (gcol & 31);
#pragma unroll
    for (int mt = 0; mt < 2; ++mt) {
#pragma unroll
      for (int r = 0; r < 4; ++r) {
        int grow = nb + mt * 16 + crow + r;
        if (grow < N) {
          float v = fmaxf(acc[mt][ot][r] + bv, 0.0f);
          __builtin_nontemporal_store(f2bf(v), &op[(size_t)grow * 32]);
        }
      }
    }
  }
}

// dec2 GEMM + fused head over panels: h=relu([agg|x]@[Wl;Wr]^T+bl) in regs;
// x_new = xprev + h@linW^T + linb; writes out[:,t,:] and xprev.
__global__ __launch_bounds__(256) void gemm128_head_mfma_kernel(
    const unsigned short* __restrict__ agg, const unsigned short* __restrict__ x,
    const unsigned short* __restrict__ Wlb, const unsigned short* __restrict__ Wrb,
    const float* __restrict__ bl, const float* __restrict__ linW,
    const float* __restrict__ linb, float* __restrict__ xprev,
    float* __restrict__ out, int N, int T, int t) {
  __shared__ float Wh[4][128];
  size_t N32 = (size_t)N * 32;
  int tid = threadIdx.x;
  for (int i = tid; i < 512; i += 256) Wh[i >> 7][i & 127] = linW[i];
  __syncthreads();

  int wave = tid >> 6;
  int lane = tid & 63;
  int nb = blockIdx.x * 128 + wave * 32;
  int l15 = lane & 15;
  int lk = (lane >> 4) * 8;

  f32x4 acc[2][8] = {};
  int r0 = nb + l15;      if (r0 > N - 1) r0 = N - 1;
  int r1 = nb + 16 + l15; if (r1 > N - 1) r1 = N - 1;

#pragma unroll
  for (int ks = 0; ks < 8; ++ks) {
    const unsigned short* P = (ks < 4) ? (agg + (size_t)ks * N32)
                                       : (x + (size_t)(ks - 4) * N32);
    short8 a0 = *(const short8*)&P[(size_t)r0 * 32 + lk];
    short8 a1 = *(const short8*)&P[(size_t)r1 * 32 + lk];
    const unsigned short* Ws = (ks < 4) ? Wlb : Wrb;
    int ko = (ks & 3) * 32 + lk;
#pragma unroll
    for (int ot = 0; ot < 8; ++ot) {
      short8 b = *(const short8*)&Ws[(ot * 16 + l15) * 128 + ko];
      acc[0][ot] = __builtin_amdgcn_mfma_f32_16x16x32_bf16(a0, b, acc[0][ot], 0, 0, 0);
      acc[1][ot] = __builtin_amdgcn_mfma_f32_16x16x32_bf16(a1, b, acc[1][ot], 0, 0, 0);
    }
  }

  float part[2][4][4] = {};
#pragma unroll
  for (int ot = 0; ot < 8; ++ot) {
    int gcol = ot * 16 + l15;
    float bv = bl[gcol];
    float w0 = Wh[0][gcol], w1 = Wh[1][gcol], w2 = Wh[2][gcol], w3 = Wh[3][gcol];
#pragma unroll
    for (int mt = 0; mt < 2; ++mt)
#pragma unroll
      for (int r = 0; r < 4; ++r) {
        float hv = fmaxf(acc[mt][ot][r] + bv, 0.0f);
        part[mt][r][0] += hv * w0;
        part[mt][r][1] += hv * w1;
        part[mt][r][2] += hv * w2;
        part[mt][r][3] += hv * w3;
      }
  }
#pragma unroll
  for (int m = 1; m < 16; m <<= 1)
#pragma unroll
    for (int mt = 0; mt < 2; ++mt)
#pragma unroll
      for (int r = 0; r < 4; ++r)
#pragma unroll
        for (int o = 0; o < 4; ++o)
          part[mt][r][o] += __shfl_xor(part[mt][r][o], m, 64);

  if (l15 == 0) {
    int crow = (lane >> 4) * 4;
    float4 lb = *(const float4*)linb;
#pragma unroll
    for (int mt = 0; mt < 2; ++mt)
#pragma unroll
      for (int r = 0; r < 4; ++r) {
        int grow = nb + mt * 16 + crow + r;
        if (grow < N) {
          float4 xp = *(const float4*)&xprev[grow * 4];
          float4 xn;
          xn.x = xp.x + part[mt][r][0] + lb.x;
          xn.y = xp.y + part[mt][r][1] + lb.y;
          xn.z = xp.z + part[mt][r][2] + lb.z;
          xn.w = xp.w + part[mt][r][3] + lb.w;
          *(float4*)&out[(grow * T + t) * 4] = xn;
          *(float4*)&xprev[grow * 4] = xn;
        }
      }
  }
}

extern "C" void kernel_launch(void* const* d_in, const int* in_sizes, int n_in,
                              void* d_out, int out_size, void* d_ws, size_t ws_size,
                              hipStream_t stream) {
  const float* F0   = (const float*)d_in[0];
  const float* mesh = (const float*)d_in[1];
  const int*   eidx = (const int*)d_in[2];
  const float* e1Wl = (const float*)d_in[4];
  const float* e1bl = (const float*)d_in[5];
  const float* e1Wr = (const float*)d_in[6];
  const float* e2Wl = (const float*)d_in[7];
  const float* e2bl = (const float*)d_in[8];
  const float* e2Wr = (const float*)d_in[9];
  const float* d1Wl = (const float*)d_in[10];
  const float* d1bl = (const float*)d_in[11];
  const float* d1Wr = (const float*)d_in[12];
  const float* d2Wl = (const float*)d_in[13];
  const float* d2bl = (const float*)d_in[14];
  const float* d2Wr = (const float*)d_in[15];
  const float* linW = (const float*)d_in[16];
  const float* linb = (const float*)d_in[17];

  const int N = in_sizes[0] / 4;
  const int E = in_sizes[2] / 2;
  const int T = out_size / (N * 4);
  const int* src = eidx;
  const int* dst = eidx + E;

  size_t off = 0;
  auto alloc = [&](size_t bytes) -> void* {
    void* p = (char*)d_ws + off;
    off += (bytes + 511) & ~(size_t)511;
    return p;
  };
  int*   cnt     = (int*)alloc((size_t)N * 4);
  int*   row_ptr = (int*)alloc((size_t)(N + 1) * 4);
  int*   rank    = (int*)alloc((size_t)E * 4);
  int*   col     = (int*)alloc((size_t)E * 4);
  float* rdeg    = (float*)alloc((size_t)N * 4);
  float* xprev   = (float*)alloc((size_t)N * 4 * 4);
  float* aggm    = (float*)alloc((size_t)N * 8 * 4);
  int*   bsum    = (int*)alloc(256 * 4);
  int*   boff    = (int*)alloc(256 * 4);
  unsigned short* mterm = (unsigned short*)alloc((size_t)N * 128 * 2);
  unsigned short* h1   = (unsigned short*)alloc((size_t)N * 128 * 2);  // 4 panels Nx32
  unsigned short* h2   = (unsigned short*)alloc((size_t)N * 128 * 2);
  unsigned short* aggb = (unsigned short*)alloc((size_t)N * 128 * 2);
  unsigned short* wb   = (unsigned short*)alloc((size_t)6 * 128 * 128 * 2);
  unsigned short* e2Wlb = wb + 0 * 16384;
  unsigned short* e2Wrb = wb + 1 * 16384;
  unsigned short* d1Wlb = wb + 2 * 16384;
  unsigned short* d1Wrb = wb + 3 * 16384;
  unsigned short* d2Wlb = wb + 4 * 16384;
  unsigned short* d2Wrb = wb + 5 * 16384;

  float* outp = (float*)d_out;

  const int NB = (N + 255) / 256;   // 196 <= 256

  // ---- once per launch: CSR + invariants ----
  hipMemsetAsync(cnt, 0, (size_t)N * 4, stream);
  count_rank_kernel<<<(E + 255) / 256, 256, 0, stream>>>(dst, cnt, rank, E);
  blocksum_kernel<<<NB, 256, 0, stream>>>(cnt, bsum, N);
  scan_sums_kernel<<<1, 256, 0, stream>>>(bsum, boff, NB);
  expand_kernel<<<NB, 256, 0, stream>>>(cnt, boff, row_ptr, rdeg, N);
  fill_csr2_kernel<<<(E + 255) / 256, 256, 0, stream>>>(src, dst, rank, row_ptr, col, E);
  f2bf6_kernel<<<(6 * 16384 + 255) / 256, 256, 0, stream>>>(
      e2Wl, e2Wr, d1Wl, d1Wr, d2Wl, d2Wr, wb);
  aggmesh_kernel<<<(N * 2 + 255) / 256, 256, 0, stream>>>(mesh, aggm, row_ptr, col, rdeg, N);
  mesh_term_kernel<<<(N * 128 + 255) / 256, 256, 0, stream>>>(aggm, mesh, e1Wl, e1Wr, e1bl,
                                                              mterm, N);
  hipMemcpyAsync(xprev, F0, (size_t)N * 4 * 4, hipMemcpyDeviceToDevice, stream);

  // agg grid: 8 XCD-pinned columns x K rows; chunk=(b>>3)*2+(b&7&1) covers
  // ceil(N/64) chunks per slice.
  const int K = ((N + 63) / 64 + 1) / 2;
  const int gAgg  = 8 * K;
  const int gGemm = (N + 127) / 128;
  const int gEnc1 = (N + 63) / 64;

  for (int t = 0; t < T; ++t) {
    enc1_kernel<<<gEnc1, 256, 0, stream>>>(xprev, row_ptr, col, rdeg,
                                           e1Wl, e1Wr, mterm, h1, N);

    agg128_sliced_kernel<<<gAgg, 256, 0, stream>>>(h1, aggb, row_ptr, col, rdeg, N);
    gemm128_mfma_kernel<<<gGemm, 256, 0, stream>>>(aggb, h1, e2Wlb, e2Wrb, e2bl, h2, N);

    agg128_sliced_kernel<<<gAgg, 256, 0, stream>>>(h2, aggb, row_ptr, col, rdeg, N);
    gemm128_mfma_kernel<<<gGemm, 256, 0, stream>>>(aggb, h2, d1Wlb, d1Wrb, d1bl, h1, N);

    agg128_sliced_kernel<<<gAgg, 256, 0, stream>>>(h1, aggb, row_ptr, col, rdeg, N);
    gemm128_head_mfma_kernel<<<gGemm, 256, 0, stream>>>(aggb, h1, d2Wlb, d2Wrb, d2bl,
                                                        linW, linb, xprev, outp, N, T, t);
  }
}

// Round 7
// 1894.831 us; speedup vs baseline: 1.0352x; 1.0352x over previous
//
#include <hip/hip_runtime.h>

// ---------------------------------------------------------------------------
// Recurrent GraphSAGE net. Round 7: R4 structure + degree-sorted agg order.
//  - R5 (fusion) and R6 (XCD slicing + nt) both regressed: the gather is
//    latency/TLP-bound; keep max-TLP separate agg kernels, no nt hints.
//  - New: nodes processed in degree-sorted order in agg128 (counting sort by
//    degree once per launch). Waves see uniform trip counts -> ~30% less
//    masked-idle time in the latency-bound gather.
// Per timestep: enc1, [agg, gemm] x2, [agg, gemm+head] = 7 dispatches.
// ---------------------------------------------------------------------------

typedef __attribute__((ext_vector_type(8))) short short8;
typedef __attribute__((ext_vector_type(8))) unsigned short ushort8;
typedef __attribute__((ext_vector_type(4))) float f32x4;

static __device__ __forceinline__ float b2f(unsigned short u) {
  return __uint_as_float(((unsigned int)u) << 16);
}
static __device__ __forceinline__ unsigned short f2bf(float f) {
  unsigned int u = __float_as_uint(f);
  u += 0x7FFFu + ((u >> 16) & 1u);   // round-nearest-even
  return (unsigned short)(u >> 16);
}

// ---------------- graph preprocessing ----------------

__global__ void count_rank_kernel(const int* __restrict__ dst, int* __restrict__ cnt,
                                  int* __restrict__ rank, int E) {
  int e = blockIdx.x * blockDim.x + threadIdx.x;
  if (e < E) rank[e] = atomicAdd(&cnt[dst[e]], 1);
}

__global__ __launch_bounds__(256) void blocksum_kernel(const int* __restrict__ cnt,
                                                       int* __restrict__ bsum, int n) {
  __shared__ int s[256];
  int tid = threadIdx.x;
  int i = blockIdx.x * 256 + tid;
  s[tid] = (i < n) ? cnt[i] : 0;
  __syncthreads();
  for (int off = 128; off > 0; off >>= 1) {
    if (tid < off) s[tid] += s[tid + off];
    __syncthreads();
  }
  if (tid == 0) bsum[blockIdx.x] = s[0];
}

__global__ __launch_bounds__(256) void scan_sums_kernel(const int* __restrict__ bsum,
                                                        int* __restrict__ boff, int nb) {
  __shared__ int s[256];
  int tid = threadIdx.x;
  int v = (tid < nb) ? bsum[tid] : 0;
  s[tid] = v;
  __syncthreads();
  for (int off = 1; off < 256; off <<= 1) {
    int t = (tid >= off) ? s[tid - off] : 0;
    __syncthreads();
    s[tid] += t;
    __syncthreads();
  }
  if (tid < nb) boff[tid] = s[tid] - v;   // exclusive
}

__global__ __launch_bounds__(256) void expand_kernel(const int* __restrict__ cnt,
                                                     const int* __restrict__ boff,
                                                     int* __restrict__ row_ptr,
                                                     float* __restrict__ rdeg, int n) {
  __shared__ int s[256];
  int tid = threadIdx.x;
  int i = blockIdx.x * 256 + tid;
  int v = (i < n) ? cnt[i] : 0;
  s[tid] = v;
  __syncthreads();
  for (int off = 1; off < 256; off <<= 1) {
    int t = (tid >= off) ? s[tid - off] : 0;
    __syncthreads();
    s[tid] += t;
    __syncthreads();
  }
  if (i < n) {
    row_ptr[i + 1] = boff[blockIdx.x] + s[tid];
    rdeg[i] = 1.0f / fmaxf((float)v, 1.0f);
  }
  if (i == 0) row_ptr[0] = 0;
}

__global__ void fill_csr2_kernel(const int* __restrict__ src, const int* __restrict__ dst,
                                 const int* __restrict__ rank, const int* __restrict__ row_ptr,
                                 int* __restrict__ col, int E) {
  int e = blockIdx.x * blockDim.x + threadIdx.x;
  if (e < E) col[row_ptr[dst[e]] + rank[e]] = src[e];
}

// ---- degree sort (counting sort, 128 bins) ----
__global__ void deg_hist_kernel(const int* __restrict__ cnt, int* __restrict__ hist, int N) {
  int n = blockIdx.x * blockDim.x + threadIdx.x;
  if (n < N) atomicAdd(&hist[min(cnt[n], 127)], 1);
}

__global__ __launch_bounds__(128) void scan128_kernel(const int* __restrict__ hist,
                                                      int* __restrict__ binoff) {
  __shared__ int s[128];
  int tid = threadIdx.x;
  int v = hist[tid];
  s[tid] = v;
  __syncthreads();
  for (int off = 1; off < 128; off <<= 1) {
    int t = (tid >= off) ? s[tid - off] : 0;
    __syncthreads();
    s[tid] += t;
    __syncthreads();
  }
  binoff[tid] = s[tid] - v;   // exclusive
}

__global__ void scatter_order_kernel(const int* __restrict__ cnt, const int* __restrict__ binoff,
                                     int* __restrict__ bincur, int* __restrict__ order, int N) {
  int n = blockIdx.x * blockDim.x + threadIdx.x;
  if (n < N) {
    int d = min(cnt[n], 127);
    int p = atomicAdd(&bincur[d], 1);
    order[binoff[d] + p] = n;
  }
}

// convert all 6 conv weight matrices (128x128 each) in one dispatch
__global__ void f2bf6_kernel(const float* __restrict__ s0, const float* __restrict__ s1,
                             const float* __restrict__ s2, const float* __restrict__ s3,
                             const float* __restrict__ s4, const float* __restrict__ s5,
                             unsigned short* __restrict__ dst) {
  int i = blockIdx.x * blockDim.x + threadIdx.x;
  if (i >= 6 * 16384) return;
  int m = i >> 14, o = i & 16383;
  const float* s;
  switch (m) {
    case 0: s = s0; break; case 1: s = s1; break; case 2: s = s2; break;
    case 3: s = s3; break; case 4: s = s4; break; default: s = s5; break;
  }
  dst[i] = f2bf(s[o]);
}

// mean-aggregate mesh (8 fp32 ch): 2 lanes/node, once per launch
__global__ void aggmesh_kernel(const float* __restrict__ mesh, float* __restrict__ aggm,
                               const int* __restrict__ row_ptr, const int* __restrict__ col,
                               const float* __restrict__ rdeg, int N) {
  int g = blockIdx.x * blockDim.x + threadIdx.x;
  int node = g >> 1, h = (g & 1) * 4;
  if (node >= N) return;
  int j0 = row_ptr[node], j1 = row_ptr[node + 1];
  float4 acc = make_float4(0.f, 0.f, 0.f, 0.f);
  int j = j0;
  for (; j + 4 <= j1; j += 4) {
    float4 v0 = *(const float4*)&mesh[col[j] * 8 + h];
    float4 v1 = *(const float4*)&mesh[col[j + 1] * 8 + h];
    float4 v2 = *(const float4*)&mesh[col[j + 2] * 8 + h];
    float4 v3 = *(const float4*)&mesh[col[j + 3] * 8 + h];
    acc.x += (v0.x + v1.x) + (v2.x + v3.x);
    acc.y += (v0.y + v1.y) + (v2.y + v3.y);
    acc.z += (v0.z + v1.z) + (v2.z + v3.z);
    acc.w += (v0.w + v1.w) + (v2.w + v3.w);
  }
  for (; j < j1; ++j) {
    float4 v0 = *(const float4*)&mesh[col[j] * 8 + h];
    acc.x += v0.x; acc.y += v0.y; acc.z += v0.z; acc.w += v0.w;
  }
  float r = rdeg[node];
  acc.x *= r; acc.y *= r; acc.z *= r; acc.w *= r;
  *(float4*)&aggm[node * 8 + h] = acc;
}

// mterm[n][o] = bl[o] + sum_k Wl[o][4+k]*aggm[n][k] + Wr[o][4+k]*mesh[n][k]
__global__ void mesh_term_kernel(const float* __restrict__ aggm, const float* __restrict__ mesh,
                                 const float* __restrict__ Wl, const float* __restrict__ Wr,
                                 const float* __restrict__ bl, unsigned short* __restrict__ mterm,
                                 int N) {
  int g = blockIdx.x * blockDim.x + threadIdx.x;
  if (g >= N * 128) return;
  int n = g >> 7, o = g & 127;
  float acc = bl[o];
#pragma unroll
  for (int k = 0; k < 8; ++k)
    acc += Wl[o * 12 + 4 + k] * aggm[n * 8 + k] + Wr[o * 12 + 4 + k] * mesh[n * 8 + k];
  mterm[g] = f2bf(acc);
}

// ---------------- per-timestep kernels ----------------

// enc1: gather xprev (float4 rows), K=8 GEMM, + mterm, relu -> bf16.
__global__ __launch_bounds__(256) void enc1_kernel(
    const float* __restrict__ xprev, const int* __restrict__ row_ptr,
    const int* __restrict__ col, const float* __restrict__ rdeg,
    const float* __restrict__ Wl, const float* __restrict__ Wr,
    const unsigned short* __restrict__ mterm, unsigned short* __restrict__ out, int N) {
  __shared__ float Wx[8][128];   // k<4: Wl[:, k]; k>=4: Wr[:, k-4]
  __shared__ float4 part[256];
  __shared__ float As[64][8];    // [node][aggx(4) | own(4)]
  int tid = threadIdx.x;
  int nb = blockIdx.x * 64;
  for (int i = tid; i < 1024; i += 256) {
    int k = i >> 7, o = i & 127;
    Wx[k][o] = (k < 4) ? Wl[o * 12 + k] : Wr[o * 12 + (k - 4)];
  }
  int nl = tid >> 2, q = tid & 3;
  int gn = nb + nl; if (gn > N - 1) gn = N - 1;
  int j0 = row_ptr[gn], j1 = row_ptr[gn + 1];
  int per = (j1 - j0 + 3) >> 2;
  int a = j0 + q * per; if (a > j1) a = j1;
  int b = a + per; if (b > j1) b = j1;
  float4 acc = make_float4(0.f, 0.f, 0.f, 0.f);
  int j = a;
  for (; j + 2 <= b; j += 2) {
    float4 v0 = *(const float4*)&xprev[col[j] * 4];
    float4 v1 = *(const float4*)&xprev[col[j + 1] * 4];
    acc.x += v0.x + v1.x; acc.y += v0.y + v1.y;
    acc.z += v0.z + v1.z; acc.w += v0.w + v1.w;
  }
  if (j < b) {
    float4 v0 = *(const float4*)&xprev[col[j] * 4];
    acc.x += v0.x; acc.y += v0.y; acc.z += v0.z; acc.w += v0.w;
  }
  part[tid] = acc;
  __syncthreads();
  if (tid < 64) {
    int g2 = nb + tid; if (g2 > N - 1) g2 = N - 1;
    float4 s0 = part[tid * 4], s1 = part[tid * 4 + 1];
    float4 s2 = part[tid * 4 + 2], s3 = part[tid * 4 + 3];
    float r = rdeg[g2];
    As[tid][0] = (s0.x + s1.x + s2.x + s3.x) * r;
    As[tid][1] = (s0.y + s1.y + s2.y + s3.y) * r;
    As[tid][2] = (s0.z + s1.z + s2.z + s3.z) * r;
    As[tid][3] = (s0.w + s1.w + s2.w + s3.w) * r;
    float4 own = *(const float4*)&xprev[g2 * 4];
    As[tid][4] = own.x; As[tid][5] = own.y; As[tid][6] = own.z; As[tid][7] = own.w;
  }
  __syncthreads();
  int gn2 = nb + nl;
  if (gn2 >= N) return;
  float av[8];
#pragma unroll
  for (int k = 0; k < 8; ++k) av[k] = As[nl][k];
  int o0 = q * 32;
#pragma unroll
  for (int c = 0; c < 4; ++c) {
    ushort8 mt = *(const ushort8*)&mterm[gn2 * 128 + o0 + c * 8];
    ushort8 ov;
#pragma unroll
    for (int oo = 0; oo < 8; ++oo) {
      int o = o0 + c * 8 + oo;
      float s = b2f(mt[oo]);
#pragma unroll
      for (int k = 0; k < 8; ++k) s += av[k] * Wx[k][o];
      ov[oo] = f2bf(fmaxf(s, 0.0f));
    }
    *(ushort8*)&out[gn2 * 128 + o0 + c * 8] = ov;
  }
}

// bf16 mean-aggregate: 16 lanes/node, ushort8/lane, unroll-8, degree-sorted order
__global__ void agg128_kernel(const unsigned short* __restrict__ feat,
                              unsigned short* __restrict__ out,
                              const int* __restrict__ row_ptr, const int* __restrict__ col,
                              const float* __restrict__ rdeg,
                              const int* __restrict__ order, int N) {
  int g = blockIdx.x * blockDim.x + threadIdx.x;
  int slot = g >> 4;
  if (slot >= N) return;
  int node = order[slot];
  int d = g & 15;
  int j0 = row_ptr[node], j1 = row_ptr[node + 1];
  float acc[8] = {};
  int j = j0;
  for (; j + 8 <= j1; j += 8) {
    ushort8 v0 = *(const ushort8*)&feat[col[j    ] * 128 + d * 8];
    ushort8 v1 = *(const ushort8*)&feat[col[j + 1] * 128 + d * 8];
    ushort8 v2 = *(const ushort8*)&feat[col[j + 2] * 128 + d * 8];
    ushort8 v3 = *(const ushort8*)&feat[col[j + 3] * 128 + d * 8];
    ushort8 v4 = *(const ushort8*)&feat[col[j + 4] * 128 + d * 8];
    ushort8 v5 = *(const ushort8*)&feat[col[j + 5] * 128 + d * 8];
    ushort8 v6 = *(const ushort8*)&feat[col[j + 6] * 128 + d * 8];
    ushort8 v7 = *(const ushort8*)&feat[col[j + 7] * 128 + d * 8];
#pragma unroll
    for (int r = 0; r < 8; ++r)
      acc[r] += ((b2f(v0[r]) + b2f(v1[r])) + (b2f(v2[r]) + b2f(v3[r]))) +
                ((b2f(v4[r]) + b2f(v5[r])) + (b2f(v6[r]) + b2f(v7[r])));
  }
  for (; j + 2 <= j1; j += 2) {
    ushort8 v0 = *(const ushort8*)&feat[col[j] * 128 + d * 8];
    ushort8 v1 = *(const ushort8*)&feat[col[j + 1] * 128 + d * 8];
#pragma unroll
    for (int r = 0; r < 8; ++r) acc[r] += b2f(v0[r]) + b2f(v1[r]);
  }
  if (j < j1) {
    ushort8 v0 = *(const ushort8*)&feat[col[j] * 128 + d * 8];
#pragma unroll
    for (int r = 0; r < 8; ++r) acc[r] += b2f(v0[r]);
  }
  float rd = rdeg[node];
  ushort8 o;
#pragma unroll
  for (int r = 0; r < 8; ++r) o[r] = f2bf(acc[r] * rd);
  *(ushort8*)&out[node * 128 + d * 8] = o;
}

// conv GEMM via MFMA: out = relu([agg|x] @ [Wl;Wr]^T + bl), bf16 in/out
__global__ __launch_bounds__(256) void gemm128_mfma_kernel(
    const unsigned short* __restrict__ agg, const unsigned short* __restrict__ x,
    const unsigned short* __restrict__ Wlb, const unsigned short* __restrict__ Wrb,
    const float* __restrict__ bl, unsigned short* __restrict__ out, int N) {
  int tid = threadIdx.x;
  int wave = tid >> 6;
  int lane = tid & 63;
  int nb = blockIdx.x * 128 + wave * 32;
  int l15 = lane & 15;
  int lk = (lane >> 4) * 8;

  f32x4 acc[2][8] = {};
  int r0 = nb + l15;      if (r0 > N - 1) r0 = N - 1;
  int r1 = nb + 16 + l15; if (r1 > N - 1) r1 = N - 1;

#pragma unroll
  for (int ks = 0; ks < 8; ++ks) {
    const unsigned short* As = (ks < 4) ? agg : x;
    const unsigned short* Ws = (ks < 4) ? Wlb : Wrb;
    int ko = (ks & 3) * 32 + lk;
    short8 a0 = *(const short8*)&As[r0 * 128 + ko];
    short8 a1 = *(const short8*)&As[r1 * 128 + ko];
#pragma unroll
    for (int ot = 0; ot < 8; ++ot) {
      short8 b = *(const short8*)&Ws[(ot * 16 + l15) * 128 + ko];
      acc[0][ot] = __builtin_amdgcn_mfma_f32_16x16x32_bf16(a0, b, acc[0][ot], 0, 0, 0);
      acc[1][ot] = __builtin_amdgcn_mfma_f32_16x16x32_bf16(a1, b, acc[1][ot], 0, 0, 0);
    }
  }

  int crow = (lane >> 4) * 4;   // C: col = lane&15, row = (lane>>4)*4 + reg
#pragma unroll
  for (int ot = 0; ot < 8; ++ot) {
    int gcol = ot * 16 + l15;
    float bv = bl[gcol];
#pragma unroll
    for (int mt = 0; mt < 2; ++mt) {
#pragma unroll
      for (int r = 0; r < 4; ++r) {
        int grow = nb + mt * 16 + crow + r;
        if (grow < N) {
          float v = fmaxf(acc[mt][ot][r] + bv, 0.0f);
          out[grow * 128 + gcol] = f2bf(v);
        }
      }
    }
  }
}

// dec2 GEMM + fused head: h = relu([agg|x]@[Wl;Wr]^T + bl);
// x_new = xprev + h@linW^T + linb; writes out[:,t,:] and xprev.
__global__ __launch_bounds__(256) void gemm128_head_mfma_kernel(
    const unsigned short* __restrict__ agg, const unsigned short* __restrict__ x,
    const unsigned short* __restrict__ Wlb, const unsigned short* __restrict__ Wrb,
    const float* __restrict__ bl, const float* __restrict__ linW,
    const float* __restrict__ linb, float* __restrict__ xprev,
    float* __restrict__ out, int N, int T, int t) {
  __shared__ float Wh[4][128];
  int tid = threadIdx.x;
  for (int i = tid; i < 512; i += 256) Wh[i >> 7][i & 127] = linW[i];
  __syncthreads();

  int wave = tid >> 6;
  int lane = tid & 63;
  int nb = blockIdx.x * 128 + wave * 32;
  int l15 = lane & 15;
  int lk = (lane >> 4) * 8;

  f32x4 acc[2][8] = {};
  int r0 = nb + l15;      if (r0 > N - 1) r0 = N - 1;
  int r1 = nb + 16 + l15; if (r1 > N - 1) r1 = N - 1;

#pragma unroll
  for (int ks = 0; ks < 8; ++ks) {
    const unsigned short* As = (ks < 4) ? agg : x;
    const unsigned short* Ws = (ks < 4) ? Wlb : Wrb;
    int ko = (ks & 3) * 32 + lk;
    short8 a0 = *(const short8*)&As[r0 * 128 + ko];
    short8 a1 = *(const short8*)&As[r1 * 128 + ko];
#pragma unroll
    for (int ot = 0; ot < 8; ++ot) {
      short8 b = *(const short8*)&Ws[(ot * 16 + l15) * 128 + ko];
      acc[0][ot] = __builtin_amdgcn_mfma_f32_16x16x32_bf16(a0, b, acc[0][ot], 0, 0, 0);
      acc[1][ot] = __builtin_amdgcn_mfma_f32_16x16x32_bf16(a1, b, acc[1][ot], 0, 0, 0);
    }
  }

  float part[2][4][4] = {};
#pragma unroll
  for (int ot = 0; ot < 8; ++ot) {
    int gcol = ot * 16 + l15;
    float bv = bl[gcol];
    float w0 = Wh[0][gcol], w1 = Wh[1][gcol], w2 = Wh[2][gcol], w3 = Wh[3][gcol];
#pragma unroll
    for (int mt = 0; mt < 2; ++mt)
#pragma unroll
      for (int r = 0; r < 4; ++r) {
        float hv = fmaxf(acc[mt][ot][r] + bv, 0.0f);
        part[mt][r][0] += hv * w0;
        part[mt][r][1] += hv * w1;
        part[mt][r][2] += hv * w2;
        part[mt][r][3] += hv * w3;
      }
  }
#pragma unroll
  for (int m = 1; m < 16; m <<= 1)
#pragma unroll
    for (int mt = 0; mt < 2; ++mt)
#pragma unroll
      for (int r = 0; r < 4; ++r)
#pragma unroll
        for (int o = 0; o < 4; ++o)
          part[mt][r][o] += __shfl_xor(part[mt][r][o], m, 64);

  if (l15 == 0) {
    int crow = (lane >> 4) * 4;
    float4 lb = *(const float4*)linb;
#pragma unroll
    for (int mt = 0; mt < 2; ++mt)
#pragma unroll
      for (int r = 0; r < 4; ++r) {
        int grow = nb + mt * 16 + crow + r;
        if (grow < N) {
          float4 xp = *(const float4*)&xprev[grow * 4];
          float4 xn;
          xn.x = xp.x + part[mt][r][0] + lb.x;
          xn.y = xp.y + part[mt][r][1] + lb.y;
          xn.z = xp.z + part[mt][r][2] + lb.z;
          xn.w = xp.w + part[mt][r][3] + lb.w;
          *(float4*)&out[(grow * T + t) * 4] = xn;
          *(float4*)&xprev[grow * 4] = xn;
        }
      }
  }
}

extern "C" void kernel_launch(void* const* d_in, const int* in_sizes, int n_in,
                              void* d_out, int out_size, void* d_ws, size_t ws_size,
                              hipStream_t stream) {
  const float* F0   = (const float*)d_in[0];
  const float* mesh = (const float*)d_in[1];
  const int*   eidx = (const int*)d_in[2];
  const float* e1Wl = (const float*)d_in[4];
  const float* e1bl = (const float*)d_in[5];
  const float* e1Wr = (const float*)d_in[6];
  const float* e2Wl = (const float*)d_in[7];
  const float* e2bl = (const float*)d_in[8];
  const float* e2Wr = (const float*)d_in[9];
  const float* d1Wl = (const float*)d_in[10];
  const float* d1bl = (const float*)d_in[11];
  const float* d1Wr = (const float*)d_in[12];
  const float* d2Wl = (const float*)d_in[13];
  const float* d2bl = (const float*)d_in[14];
  const float* d2Wr = (const float*)d_in[15];
  const float* linW = (const float*)d_in[16];
  const float* linb = (const float*)d_in[17];

  const int N = in_sizes[0] / 4;
  const int E = in_sizes[2] / 2;
  const int T = out_size / (N * 4);
  const int* src = eidx;
  const int* dst = eidx + E;

  size_t off = 0;
  auto alloc = [&](size_t bytes) -> void* {
    void* p = (char*)d_ws + off;
    off += (bytes + 511) & ~(size_t)511;
    return p;
  };
  int*   cnt     = (int*)alloc((size_t)N * 4);
  int*   row_ptr = (int*)alloc((size_t)(N + 1) * 4);
  int*   rank    = (int*)alloc((size_t)E * 4);
  int*   col     = (int*)alloc((size_t)E * 4);
  float* rdeg    = (float*)alloc((size_t)N * 4);
  float* xprev   = (float*)alloc((size_t)N * 4 * 4);
  float* aggm    = (float*)alloc((size_t)N * 8 * 4);
  int*   bsum    = (int*)alloc(256 * 4);
  int*   boff    = (int*)alloc(256 * 4);
  int*   hist    = (int*)alloc(128 * 4);
  int*   binoff  = (int*)alloc(128 * 4);
  int*   bincur  = (int*)alloc(128 * 4);
  int*   order   = (int*)alloc((size_t)N * 4);
  unsigned short* mterm = (unsigned short*)alloc((size_t)N * 128 * 2);
  unsigned short* h1   = (unsigned short*)alloc((size_t)N * 128 * 2);
  unsigned short* h2   = (unsigned short*)alloc((size_t)N * 128 * 2);
  unsigned short* aggb = (unsigned short*)alloc((size_t)N * 128 * 2);
  unsigned short* wb   = (unsigned short*)alloc((size_t)6 * 128 * 128 * 2);
  unsigned short* e2Wlb = wb + 0 * 16384;
  unsigned short* e2Wrb = wb + 1 * 16384;
  unsigned short* d1Wlb = wb + 2 * 16384;
  unsigned short* d1Wrb = wb + 3 * 16384;
  unsigned short* d2Wlb = wb + 4 * 16384;
  unsigned short* d2Wrb = wb + 5 * 16384;

  float* outp = (float*)d_out;

  const int NB = (N + 255) / 256;   // 196 <= 256

  // ---- once per launch: CSR + degree sort + invariants ----
  hipMemsetAsync(cnt, 0, (size_t)N * 4, stream);
  hipMemsetAsync(hist, 0, 128 * 4, stream);
  hipMemsetAsync(bincur, 0, 128 * 4, stream);
  count_rank_kernel<<<(E + 255) / 256, 256, 0, stream>>>(dst, cnt, rank, E);
  blocksum_kernel<<<NB, 256, 0, stream>>>(cnt, bsum, N);
  scan_sums_kernel<<<1, 256, 0, stream>>>(bsum, boff, NB);
  expand_kernel<<<NB, 256, 0, stream>>>(cnt, boff, row_ptr, rdeg, N);
  fill_csr2_kernel<<<(E + 255) / 256, 256, 0, stream>>>(src, dst, rank, row_ptr, col, E);
  deg_hist_kernel<<<NB, 256, 0, stream>>>(cnt, hist, N);
  scan128_kernel<<<1, 128, 0, stream>>>(hist, binoff);
  scatter_order_kernel<<<NB, 256, 0, stream>>>(cnt, binoff, bincur, order, N);
  f2bf6_kernel<<<(6 * 16384 + 255) / 256, 256, 0, stream>>>(
      e2Wl, e2Wr, d1Wl, d1Wr, d2Wl, d2Wr, wb);
  aggmesh_kernel<<<(N * 2 + 255) / 256, 256, 0, stream>>>(mesh, aggm, row_ptr, col, rdeg, N);
  mesh_term_kernel<<<(N * 128 + 255) / 256, 256, 0, stream>>>(aggm, mesh, e1Wl, e1Wr, e1bl,
                                                              mterm, N);
  hipMemcpyAsync(xprev, F0, (size_t)N * 4 * 4, hipMemcpyDeviceToDevice, stream);

  const int gAgg  = (N * 16 + 255) / 256;
  const int gGemm = (N + 127) / 128;
  const int gEnc1 = (N + 63) / 64;

  for (int t = 0; t < T; ++t) {
    enc1_kernel<<<gEnc1, 256, 0, stream>>>(xprev, row_ptr, col, rdeg,
                                           e1Wl, e1Wr, mterm, h1, N);

    agg128_kernel<<<gAgg, 256, 0, stream>>>(h1, aggb, row_ptr, col, rdeg, order, N);
    gemm128_mfma_kernel<<<gGemm, 256, 0, stream>>>(aggb, h1, e2Wlb, e2Wrb, e2bl, h2, N);

    agg128_kernel<<<gAgg, 256, 0, stream>>>(h2, aggb, row_ptr, col, rdeg, order, N);
    gemm128_mfma_kernel<<<gGemm, 256, 0, stream>>>(aggb, h2, d1Wlb, d1Wrb, d1bl, h1, N);

    agg128_kernel<<<gAgg, 256, 0, stream>>>(h1, aggb, row_ptr, col, rdeg, order, N);
    gemm128_head_mfma_kernel<<<gGemm, 256, 0, stream>>>(aggb, h1, d2Wlb, d2Wrb, d2bl,
                                                        linW, linb, xprev, outp, N, T, t);
  }
}

// Round 8
// 1846.490 us; speedup vs baseline: 1.0623x; 1.0262x over previous
//
#include <hip/hip_runtime.h>

// ---------------------------------------------------------------------------
// Recurrent GraphSAGE net. Round 8: R4 structure + high-occupancy GEMMs.
//  - agg128 at its practical plateau (~9-10 TB/s random row gather): R4
//    unroll-8 neutral, R5 fusion -2x, R6 slicing -2x, R7 deg-sort null.
//    Keep R4's max-TLP 16-lane/node gather untouched.
//  - gemm/head: 512-thread blocks, 8 waves x 16 nodes (was 4 waves x 32):
//    same 128-node block (B amortization unchanged), 2x resident waves
//    (19% -> 38% occupancy) to hide A-load latency.
// Per timestep: enc1, [agg, gemm] x2, [agg, gemm+head] = 7 dispatches.
// ---------------------------------------------------------------------------

typedef __attribute__((ext_vector_type(8))) short short8;
typedef __attribute__((ext_vector_type(8))) unsigned short ushort8;
typedef __attribute__((ext_vector_type(4))) float f32x4;

static __device__ __forceinline__ float b2f(unsigned short u) {
  return __uint_as_float(((unsigned int)u) << 16);
}
static __device__ __forceinline__ unsigned short f2bf(float f) {
  unsigned int u = __float_as_uint(f);
  u += 0x7FFFu + ((u >> 16) & 1u);   // round-nearest-even
  return (unsigned short)(u >> 16);
}

// ---------------- graph preprocessing ----------------

__global__ void count_rank_kernel(const int* __restrict__ dst, int* __restrict__ cnt,
                                  int* __restrict__ rank, int E) {
  int e = blockIdx.x * blockDim.x + threadIdx.x;
  if (e < E) rank[e] = atomicAdd(&cnt[dst[e]], 1);
}

__global__ __launch_bounds__(256) void blocksum_kernel(const int* __restrict__ cnt,
                                                       int* __restrict__ bsum, int n) {
  __shared__ int s[256];
  int tid = threadIdx.x;
  int i = blockIdx.x * 256 + tid;
  s[tid] = (i < n) ? cnt[i] : 0;
  __syncthreads();
  for (int off = 128; off > 0; off >>= 1) {
    if (tid < off) s[tid] += s[tid + off];
    __syncthreads();
  }
  if (tid == 0) bsum[blockIdx.x] = s[0];
}

__global__ __launch_bounds__(256) void scan_sums_kernel(const int* __restrict__ bsum,
                                                        int* __restrict__ boff, int nb) {
  __shared__ int s[256];
  int tid = threadIdx.x;
  int v = (tid < nb) ? bsum[tid] : 0;
  s[tid] = v;
  __syncthreads();
  for (int off = 1; off < 256; off <<= 1) {
    int t = (tid >= off) ? s[tid - off] : 0;
    __syncthreads();
    s[tid] += t;
    __syncthreads();
  }
  if (tid < nb) boff[tid] = s[tid] - v;   // exclusive
}

__global__ __launch_bounds__(256) void expand_kernel(const int* __restrict__ cnt,
                                                     const int* __restrict__ boff,
                                                     int* __restrict__ row_ptr,
                                                     float* __restrict__ rdeg, int n) {
  __shared__ int s[256];
  int tid = threadIdx.x;
  int i = blockIdx.x * 256 + tid;
  int v = (i < n) ? cnt[i] : 0;
  s[tid] = v;
  __syncthreads();
  for (int off = 1; off < 256; off <<= 1) {
    int t = (tid >= off) ? s[tid - off] : 0;
    __syncthreads();
    s[tid] += t;
    __syncthreads();
  }
  if (i < n) {
    row_ptr[i + 1] = boff[blockIdx.x] + s[tid];
    rdeg[i] = 1.0f / fmaxf((float)v, 1.0f);
  }
  if (i == 0) row_ptr[0] = 0;
}

__global__ void fill_csr2_kernel(const int* __restrict__ src, const int* __restrict__ dst,
                                 const int* __restrict__ rank, const int* __restrict__ row_ptr,
                                 int* __restrict__ col, int E) {
  int e = blockIdx.x * blockDim.x + threadIdx.x;
  if (e < E) col[row_ptr[dst[e]] + rank[e]] = src[e];
}

// convert all 6 conv weight matrices (128x128 each) in one dispatch
__global__ void f2bf6_kernel(const float* __restrict__ s0, const float* __restrict__ s1,
                             const float* __restrict__ s2, const float* __restrict__ s3,
                             const float* __restrict__ s4, const float* __restrict__ s5,
                             unsigned short* __restrict__ dst) {
  int i = blockIdx.x * blockDim.x + threadIdx.x;
  if (i >= 6 * 16384) return;
  int m = i >> 14, o = i & 16383;
  const float* s;
  switch (m) {
    case 0: s = s0; break; case 1: s = s1; break; case 2: s = s2; break;
    case 3: s = s3; break; case 4: s = s4; break; default: s = s5; break;
  }
  dst[i] = f2bf(s[o]);
}

// mean-aggregate mesh (8 fp32 ch): 2 lanes/node, once per launch
__global__ void aggmesh_kernel(const float* __restrict__ mesh, float* __restrict__ aggm,
                               const int* __restrict__ row_ptr, const int* __restrict__ col,
                               const float* __restrict__ rdeg, int N) {
  int g = blockIdx.x * blockDim.x + threadIdx.x;
  int node = g >> 1, h = (g & 1) * 4;
  if (node >= N) return;
  int j0 = row_ptr[node], j1 = row_ptr[node + 1];
  float4 acc = make_float4(0.f, 0.f, 0.f, 0.f);
  int j = j0;
  for (; j + 4 <= j1; j += 4) {
    float4 v0 = *(const float4*)&mesh[col[j] * 8 + h];
    float4 v1 = *(const float4*)&mesh[col[j + 1] * 8 + h];
    float4 v2 = *(const float4*)&mesh[col[j + 2] * 8 + h];
    float4 v3 = *(const float4*)&mesh[col[j + 3] * 8 + h];
    acc.x += (v0.x + v1.x) + (v2.x + v3.x);
    acc.y += (v0.y + v1.y) + (v2.y + v3.y);
    acc.z += (v0.z + v1.z) + (v2.z + v3.z);
    acc.w += (v0.w + v1.w) + (v2.w + v3.w);
  }
  for (; j < j1; ++j) {
    float4 v0 = *(const float4*)&mesh[col[j] * 8 + h];
    acc.x += v0.x; acc.y += v0.y; acc.z += v0.z; acc.w += v0.w;
  }
  float r = rdeg[node];
  acc.x *= r; acc.y *= r; acc.z *= r; acc.w *= r;
  *(float4*)&aggm[node * 8 + h] = acc;
}

// mterm[n][o] = bl[o] + sum_k Wl[o][4+k]*aggm[n][k] + Wr[o][4+k]*mesh[n][k]
__global__ void mesh_term_kernel(const float* __restrict__ aggm, const float* __restrict__ mesh,
                                 const float* __restrict__ Wl, const float* __restrict__ Wr,
                                 const float* __restrict__ bl, unsigned short* __restrict__ mterm,
                                 int N) {
  int g = blockIdx.x * blockDim.x + threadIdx.x;
  if (g >= N * 128) return;
  int n = g >> 7, o = g & 127;
  float acc = bl[o];
#pragma unroll
  for (int k = 0; k < 8; ++k)
    acc += Wl[o * 12 + 4 + k] * aggm[n * 8 + k] + Wr[o * 12 + 4 + k] * mesh[n * 8 + k];
  mterm[g] = f2bf(acc);
}

// ---------------- per-timestep kernels ----------------

// enc1: gather xprev (float4 rows), K=8 GEMM, + mterm, relu -> bf16.
__global__ __launch_bounds__(256) void enc1_kernel(
    const float* __restrict__ xprev, const int* __restrict__ row_ptr,
    const int* __restrict__ col, const float* __restrict__ rdeg,
    const float* __restrict__ Wl, const float* __restrict__ Wr,
    const unsigned short* __restrict__ mterm, unsigned short* __restrict__ out, int N) {
  __shared__ float Wx[8][128];   // k<4: Wl[:, k]; k>=4: Wr[:, k-4]
  __shared__ float4 part[256];
  __shared__ float As[64][8];    // [node][aggx(4) | own(4)]
  int tid = threadIdx.x;
  int nb = blockIdx.x * 64;
  for (int i = tid; i < 1024; i += 256) {
    int k = i >> 7, o = i & 127;
    Wx[k][o] = (k < 4) ? Wl[o * 12 + k] : Wr[o * 12 + (k - 4)];
  }
  int nl = tid >> 2, q = tid & 3;
  int gn = nb + nl; if (gn > N - 1) gn = N - 1;
  int j0 = row_ptr[gn], j1 = row_ptr[gn + 1];
  int per = (j1 - j0 + 3) >> 2;
  int a = j0 + q * per; if (a > j1) a = j1;
  int b = a + per; if (b > j1) b = j1;
  float4 acc = make_float4(0.f, 0.f, 0.f, 0.f);
  int j = a;
  for (; j + 2 <= b; j += 2) {
    float4 v0 = *(const float4*)&xprev[col[j] * 4];
    float4 v1 = *(const float4*)&xprev[col[j + 1] * 4];
    acc.x += v0.x + v1.x; acc.y += v0.y + v1.y;
    acc.z += v0.z + v1.z; acc.w += v0.w + v1.w;
  }
  if (j < b) {
    float4 v0 = *(const float4*)&xprev[col[j] * 4];
    acc.x += v0.x; acc.y += v0.y; acc.z += v0.z; acc.w += v0.w;
  }
  part[tid] = acc;
  __syncthreads();
  if (tid < 64) {
    int g2 = nb + tid; if (g2 > N - 1) g2 = N - 1;
    float4 s0 = part[tid * 4], s1 = part[tid * 4 + 1];
    float4 s2 = part[tid * 4 + 2], s3 = part[tid * 4 + 3];
    float r = rdeg[g2];
    As[tid][0] = (s0.x + s1.x + s2.x + s3.x) * r;
    As[tid][1] = (s0.y + s1.y + s2.y + s3.y) * r;
    As[tid][2] = (s0.z + s1.z + s2.z + s3.z) * r;
    As[tid][3] = (s0.w + s1.w + s2.w + s3.w) * r;
    float4 own = *(const float4*)&xprev[g2 * 4];
    As[tid][4] = own.x; As[tid][5] = own.y; As[tid][6] = own.z; As[tid][7] = own.w;
  }
  __syncthreads();
  int gn2 = nb + nl;
  if (gn2 >= N) return;
  float av[8];
#pragma unroll
  for (int k = 0; k < 8; ++k) av[k] = As[nl][k];
  int o0 = q * 32;
#pragma unroll
  for (int c = 0; c < 4; ++c) {
    ushort8 mt = *(const ushort8*)&mterm[gn2 * 128 + o0 + c * 8];
    ushort8 ov;
#pragma unroll
    for (int oo = 0; oo < 8; ++oo) {
      int o = o0 + c * 8 + oo;
      float s = b2f(mt[oo]);
#pragma unroll
      for (int k = 0; k < 8; ++k) s += av[k] * Wx[k][o];
      ov[oo] = f2bf(fmaxf(s, 0.0f));
    }
    *(ushort8*)&out[gn2 * 128 + o0 + c * 8] = ov;
  }
}

// bf16 mean-aggregate: 16 lanes/node, ushort8/lane, unroll-8 (R4 hot path)
__global__ void agg128_kernel(const unsigned short* __restrict__ feat,
                              unsigned short* __restrict__ out,
                              const int* __restrict__ row_ptr, const int* __restrict__ col,
                              const float* __restrict__ rdeg, int N) {
  int g = blockIdx.x * blockDim.x + threadIdx.x;
  int node = g >> 4;
  int d = g & 15;
  if (node >= N) return;
  int j0 = row_ptr[node], j1 = row_ptr[node + 1];
  float acc[8] = {};
  int j = j0;
  for (; j + 8 <= j1; j += 8) {
    ushort8 v0 = *(const ushort8*)&feat[col[j    ] * 128 + d * 8];
    ushort8 v1 = *(const ushort8*)&feat[col[j + 1] * 128 + d * 8];
    ushort8 v2 = *(const ushort8*)&feat[col[j + 2] * 128 + d * 8];
    ushort8 v3 = *(const ushort8*)&feat[col[j + 3] * 128 + d * 8];
    ushort8 v4 = *(const ushort8*)&feat[col[j + 4] * 128 + d * 8];
    ushort8 v5 = *(const ushort8*)&feat[col[j + 5] * 128 + d * 8];
    ushort8 v6 = *(const ushort8*)&feat[col[j + 6] * 128 + d * 8];
    ushort8 v7 = *(const ushort8*)&feat[col[j + 7] * 128 + d * 8];
#pragma unroll
    for (int r = 0; r < 8; ++r)
      acc[r] += ((b2f(v0[r]) + b2f(v1[r])) + (b2f(v2[r]) + b2f(v3[r]))) +
                ((b2f(v4[r]) + b2f(v5[r])) + (b2f(v6[r]) + b2f(v7[r])));
  }
  for (; j + 2 <= j1; j += 2) {
    ushort8 v0 = *(const ushort8*)&feat[col[j] * 128 + d * 8];
    ushort8 v1 = *(const ushort8*)&feat[col[j + 1] * 128 + d * 8];
#pragma unroll
    for (int r = 0; r < 8; ++r) acc[r] += b2f(v0[r]) + b2f(v1[r]);
  }
  if (j < j1) {
    ushort8 v0 = *(const ushort8*)&feat[col[j] * 128 + d * 8];
#pragma unroll
    for (int r = 0; r < 8; ++r) acc[r] += b2f(v0[r]);
  }
  float rd = rdeg[node];
  ushort8 o;
#pragma unroll
  for (int r = 0; r < 8; ++r) o[r] = f2bf(acc[r] * rd);
  *(ushort8*)&out[node * 128 + d * 8] = o;
}

// conv GEMM via MFMA: out = relu([agg|x] @ [Wl;Wr]^T + bl), bf16 in/out.
// 512 threads = 8 waves x 16 nodes; block = 128 nodes (B amortization kept).
__global__ __launch_bounds__(512) void gemm128_mfma_kernel(
    const unsigned short* __restrict__ agg, const unsigned short* __restrict__ x,
    const unsigned short* __restrict__ Wlb, const unsigned short* __restrict__ Wrb,
    const float* __restrict__ bl, unsigned short* __restrict__ out, int N) {
  int tid = threadIdx.x;
  int wave = tid >> 6;
  int lane = tid & 63;
  int nb = blockIdx.x * 128 + wave * 16;
  int l15 = lane & 15;
  int lk = (lane >> 4) * 8;

  f32x4 acc[8] = {};
  int r0 = nb + l15; if (r0 > N - 1) r0 = N - 1;

#pragma unroll
  for (int ks = 0; ks < 8; ++ks) {
    const unsigned short* As = (ks < 4) ? agg : x;
    const unsigned short* Ws = (ks < 4) ? Wlb : Wrb;
    int ko = (ks & 3) * 32 + lk;
    short8 a0 = *(const short8*)&As[r0 * 128 + ko];
#pragma unroll
    for (int ot = 0; ot < 8; ++ot) {
      short8 b = *(const short8*)&Ws[(ot * 16 + l15) * 128 + ko];
      acc[ot] = __builtin_amdgcn_mfma_f32_16x16x32_bf16(a0, b, acc[ot], 0, 0, 0);
    }
  }

  int crow = (lane >> 4) * 4;   // C: col = lane&15, row = (lane>>4)*4 + reg
#pragma unroll
  for (int ot = 0; ot < 8; ++ot) {
    int gcol = ot * 16 + l15;
    float bv = bl[gcol];
#pragma unroll
    for (int r = 0; r < 4; ++r) {
      int grow = nb + crow + r;
      if (grow < N) {
        float v = fmaxf(acc[ot][r] + bv, 0.0f);
        out[grow * 128 + gcol] = f2bf(v);
      }
    }
  }
}

// dec2 GEMM + fused head: h = relu([agg|x]@[Wl;Wr]^T + bl);
// x_new = xprev + h@linW^T + linb; writes out[:,t,:] and xprev.
// 512 threads = 8 waves x 16 nodes.
__global__ __launch_bounds__(512) void gemm128_head_mfma_kernel(
    const unsigned short* __restrict__ agg, const unsigned short* __restrict__ x,
    const unsigned short* __restrict__ Wlb, const unsigned short* __restrict__ Wrb,
    const float* __restrict__ bl, const float* __restrict__ linW,
    const float* __restrict__ linb, float* __restrict__ xprev,
    float* __restrict__ out, int N, int T, int t) {
  __shared__ float Wh[4][128];
  int tid = threadIdx.x;
  if (tid < 512) { int i = tid; Wh[i >> 7][i & 127] = linW[i]; }
  __syncthreads();

  int wave = tid >> 6;
  int lane = tid & 63;
  int nb = blockIdx.x * 128 + wave * 16;
  int l15 = lane & 15;
  int lk = (lane >> 4) * 8;

  f32x4 acc[8] = {};
  int r0 = nb + l15; if (r0 > N - 1) r0 = N - 1;

#pragma unroll
  for (int ks = 0; ks < 8; ++ks) {
    const unsigned short* As = (ks < 4) ? agg : x;
    const unsigned short* Ws = (ks < 4) ? Wlb : Wrb;
    int ko = (ks & 3) * 32 + lk;
    short8 a0 = *(const short8*)&As[r0 * 128 + ko];
#pragma unroll
    for (int ot = 0; ot < 8; ++ot) {
      short8 b = *(const short8*)&Ws[(ot * 16 + l15) * 128 + ko];
      acc[ot] = __builtin_amdgcn_mfma_f32_16x16x32_bf16(a0, b, acc[ot], 0, 0, 0);
    }
  }

  // head: part[r][o] = sum_col relu(h) * linW[o][col], col = ot*16+l15
  float part[4][4] = {};
#pragma unroll
  for (int ot = 0; ot < 8; ++ot) {
    int gcol = ot * 16 + l15;
    float bv = bl[gcol];
    float w0 = Wh[0][gcol], w1 = Wh[1][gcol], w2 = Wh[2][gcol], w3 = Wh[3][gcol];
#pragma unroll
    for (int r = 0; r < 4; ++r) {
      float hv = fmaxf(acc[ot][r] + bv, 0.0f);
      part[r][0] += hv * w0;
      part[r][1] += hv * w1;
      part[r][2] += hv * w2;
      part[r][3] += hv * w3;
    }
  }
  // reduce across the 16 lanes of each row group (xor stays within group)
#pragma unroll
  for (int m = 1; m < 16; m <<= 1)
#pragma unroll
    for (int r = 0; r < 4; ++r)
#pragma unroll
      for (int o = 0; o < 4; ++o)
        part[r][o] += __shfl_xor(part[r][o], m, 64);

  if (l15 == 0) {
    int crow = (lane >> 4) * 4;
    float4 lb = *(const float4*)linb;
#pragma unroll
    for (int r = 0; r < 4; ++r) {
      int grow = nb + crow + r;
      if (grow < N) {
        float4 xp = *(const float4*)&xprev[grow * 4];
        float4 xn;
        xn.x = xp.x + part[r][0] + lb.x;
        xn.y = xp.y + part[r][1] + lb.y;
        xn.z = xp.z + part[r][2] + lb.z;
        xn.w = xp.w + part[r][3] + lb.w;
        *(float4*)&out[(grow * T + t) * 4] = xn;
        *(float4*)&xprev[grow * 4] = xn;
      }
    }
  }
}

extern "C" void kernel_launch(void* const* d_in, const int* in_sizes, int n_in,
                              void* d_out, int out_size, void* d_ws, size_t ws_size,
                              hipStream_t stream) {
  const float* F0   = (const float*)d_in[0];
  const float* mesh = (const float*)d_in[1];
  const int*   eidx = (const int*)d_in[2];
  const float* e1Wl = (const float*)d_in[4];
  const float* e1bl = (const float*)d_in[5];
  const float* e1Wr = (const float*)d_in[6];
  const float* e2Wl = (const float*)d_in[7];
  const float* e2bl = (const float*)d_in[8];
  const float* e2Wr = (const float*)d_in[9];
  const float* d1Wl = (const float*)d_in[10];
  const float* d1bl = (const float*)d_in[11];
  const float* d1Wr = (const float*)d_in[12];
  const float* d2Wl = (const float*)d_in[13];
  const float* d2bl = (const float*)d_in[14];
  const float* d2Wr = (const float*)d_in[15];
  const float* linW = (const float*)d_in[16];
  const float* linb = (const float*)d_in[17];

  const int N = in_sizes[0] / 4;
  const int E = in_sizes[2] / 2;
  const int T = out_size / (N * 4);
  const int* src = eidx;
  const int* dst = eidx + E;

  size_t off = 0;
  auto alloc = [&](size_t bytes) -> void* {
    void* p = (char*)d_ws + off;
    off += (bytes + 511) & ~(size_t)511;
    return p;
  };
  int*   cnt     = (int*)alloc((size_t)N * 4);
  int*   row_ptr = (int*)alloc((size_t)(N + 1) * 4);
  int*   rank    = (int*)alloc((size_t)E * 4);
  int*   col     = (int*)alloc((size_t)E * 4);
  float* rdeg    = (float*)alloc((size_t)N * 4);
  float* xprev   = (float*)alloc((size_t)N * 4 * 4);
  float* aggm    = (float*)alloc((size_t)N * 8 * 4);
  int*   bsum    = (int*)alloc(256 * 4);
  int*   boff    = (int*)alloc(256 * 4);
  unsigned short* mterm = (unsigned short*)alloc((size_t)N * 128 * 2);
  unsigned short* h1   = (unsigned short*)alloc((size_t)N * 128 * 2);
  unsigned short* h2   = (unsigned short*)alloc((size_t)N * 128 * 2);
  unsigned short* aggb = (unsigned short*)alloc((size_t)N * 128 * 2);
  unsigned short* wb   = (unsigned short*)alloc((size_t)6 * 128 * 128 * 2);
  unsigned short* e2Wlb = wb + 0 * 16384;
  unsigned short* e2Wrb = wb + 1 * 16384;
  unsigned short* d1Wlb = wb + 2 * 16384;
  unsigned short* d1Wrb = wb + 3 * 16384;
  unsigned short* d2Wlb = wb + 4 * 16384;
  unsigned short* d2Wrb = wb + 5 * 16384;

  float* outp = (float*)d_out;

  const int NB = (N + 255) / 256;   // 196 <= 256

  // ---- once per launch: CSR + invariants ----
  hipMemsetAsync(cnt, 0, (size_t)N * 4, stream);
  count_rank_kernel<<<(E + 255) / 256, 256, 0, stream>>>(dst, cnt, rank, E);
  blocksum_kernel<<<NB, 256, 0, stream>>>(cnt, bsum, N);
  scan_sums_kernel<<<1, 256, 0, stream>>>(bsum, boff, NB);
  expand_kernel<<<NB, 256, 0, stream>>>(cnt, boff, row_ptr, rdeg, N);
  fill_csr2_kernel<<<(E + 255) / 256, 256, 0, stream>>>(src, dst, rank, row_ptr, col, E);
  f2bf6_kernel<<<(6 * 16384 + 255) / 256, 256, 0, stream>>>(
      e2Wl, e2Wr, d1Wl, d1Wr, d2Wl, d2Wr, wb);
  aggmesh_kernel<<<(N * 2 + 255) / 256, 256, 0, stream>>>(mesh, aggm, row_ptr, col, rdeg, N);
  mesh_term_kernel<<<(N * 128 + 255) / 256, 256, 0, stream>>>(aggm, mesh, e1Wl, e1Wr, e1bl,
                                                              mterm, N);
  hipMemcpyAsync(xprev, F0, (size_t)N * 4 * 4, hipMemcpyDeviceToDevice, stream);

  const int gAgg  = (N * 16 + 255) / 256;
  const int gGemm = (N + 127) / 128;
  const int gEnc1 = (N + 63) / 64;

  for (int t = 0; t < T; ++t) {
    enc1_kernel<<<gEnc1, 256, 0, stream>>>(xprev, row_ptr, col, rdeg,
                                           e1Wl, e1Wr, mterm, h1, N);

    agg128_kernel<<<gAgg, 256, 0, stream>>>(h1, aggb, row_ptr, col, rdeg, N);
    gemm128_mfma_kernel<<<gGemm, 512, 0, stream>>>(aggb, h1, e2Wlb, e2Wrb, e2bl, h2, N);

    agg128_kernel<<<gAgg, 256, 0, stream>>>(h2, aggb, row_ptr, col, rdeg, N);
    gemm128_mfma_kernel<<<gGemm, 512, 0, stream>>>(aggb, h2, d1Wlb, d1Wrb, d1bl, h1, N);

    agg128_kernel<<<gAgg, 256, 0, stream>>>(h1, aggb, row_ptr, col, rdeg, N);
    gemm128_head_mfma_kernel<<<gGemm, 512, 0, stream>>>(aggb, h1, d2Wlb, d2Wrb, d2bl,
                                                        linW, linb, xprev, outp, N, T, t);
  }
}

// Round 9
// 1742.820 us; speedup vs baseline: 1.1255x; 1.0595x over previous
//
#include <hip/hip_runtime.h>

// ---------------------------------------------------------------------------
// Recurrent GraphSAGE net. Round 9: R4 structure, GEMM with 2x B amortization.
//  - agg128 at its practical plateau (~9-10 TB/s random row gather): R4
//    unroll-8 neutral, R5 fusion -2x, R6 slicing -2x, R7 deg-sort null.
//  - R8 proved GEMM is B-traffic-bound, NOT occupancy-bound (2x waves with
//    2x B-traffic => +8.5us/dispatch). So: 4 waves x 64 nodes (block=256
//    nodes), halving B-traffic per dispatch vs R4. Head kernel = R4 exact.
// Per timestep: enc1, [agg, gemm] x2, [agg, gemm+head] = 7 dispatches.
// ---------------------------------------------------------------------------

typedef __attribute__((ext_vector_type(8))) short short8;
typedef __attribute__((ext_vector_type(8))) unsigned short ushort8;
typedef __attribute__((ext_vector_type(4))) float f32x4;

static __device__ __forceinline__ float b2f(unsigned short u) {
  return __uint_as_float(((unsigned int)u) << 16);
}
static __device__ __forceinline__ unsigned short f2bf(float f) {
  unsigned int u = __float_as_uint(f);
  u += 0x7FFFu + ((u >> 16) & 1u);   // round-nearest-even
  return (unsigned short)(u >> 16);
}

// ---------------- graph preprocessing ----------------

__global__ void count_rank_kernel(const int* __restrict__ dst, int* __restrict__ cnt,
                                  int* __restrict__ rank, int E) {
  int e = blockIdx.x * blockDim.x + threadIdx.x;
  if (e < E) rank[e] = atomicAdd(&cnt[dst[e]], 1);
}

__global__ __launch_bounds__(256) void blocksum_kernel(const int* __restrict__ cnt,
                                                       int* __restrict__ bsum, int n) {
  __shared__ int s[256];
  int tid = threadIdx.x;
  int i = blockIdx.x * 256 + tid;
  s[tid] = (i < n) ? cnt[i] : 0;
  __syncthreads();
  for (int off = 128; off > 0; off >>= 1) {
    if (tid < off) s[tid] += s[tid + off];
    __syncthreads();
  }
  if (tid == 0) bsum[blockIdx.x] = s[0];
}

__global__ __launch_bounds__(256) void scan_sums_kernel(const int* __restrict__ bsum,
                                                        int* __restrict__ boff, int nb) {
  __shared__ int s[256];
  int tid = threadIdx.x;
  int v = (tid < nb) ? bsum[tid] : 0;
  s[tid] = v;
  __syncthreads();
  for (int off = 1; off < 256; off <<= 1) {
    int t = (tid >= off) ? s[tid - off] : 0;
    __syncthreads();
    s[tid] += t;
    __syncthreads();
  }
  if (tid < nb) boff[tid] = s[tid] - v;   // exclusive
}

__global__ __launch_bounds__(256) void expand_kernel(const int* __restrict__ cnt,
                                                     const int* __restrict__ boff,
                                                     int* __restrict__ row_ptr,
                                                     float* __restrict__ rdeg, int n) {
  __shared__ int s[256];
  int tid = threadIdx.x;
  int i = blockIdx.x * 256 + tid;
  int v = (i < n) ? cnt[i] : 0;
  s[tid] = v;
  __syncthreads();
  for (int off = 1; off < 256; off <<= 1) {
    int t = (tid >= off) ? s[tid - off] : 0;
    __syncthreads();
    s[tid] += t;
    __syncthreads();
  }
  if (i < n) {
    row_ptr[i + 1] = boff[blockIdx.x] + s[tid];
    rdeg[i] = 1.0f / fmaxf((float)v, 1.0f);
  }
  if (i == 0) row_ptr[0] = 0;
}

__global__ void fill_csr2_kernel(const int* __restrict__ src, const int* __restrict__ dst,
                                 const int* __restrict__ rank, const int* __restrict__ row_ptr,
                                 int* __restrict__ col, int E) {
  int e = blockIdx.x * blockDim.x + threadIdx.x;
  if (e < E) col[row_ptr[dst[e]] + rank[e]] = src[e];
}

// convert all 6 conv weight matrices (128x128 each) in one dispatch
__global__ void f2bf6_kernel(const float* __restrict__ s0, const float* __restrict__ s1,
                             const float* __restrict__ s2, const float* __restrict__ s3,
                             const float* __restrict__ s4, const float* __restrict__ s5,
                             unsigned short* __restrict__ dst) {
  int i = blockIdx.x * blockDim.x + threadIdx.x;
  if (i >= 6 * 16384) return;
  int m = i >> 14, o = i & 16383;
  const float* s;
  switch (m) {
    case 0: s = s0; break; case 1: s = s1; break; case 2: s = s2; break;
    case 3: s = s3; break; case 4: s = s4; break; default: s = s5; break;
  }
  dst[i] = f2bf(s[o]);
}

// mean-aggregate mesh (8 fp32 ch): 2 lanes/node, once per launch
__global__ void aggmesh_kernel(const float* __restrict__ mesh, float* __restrict__ aggm,
                               const int* __restrict__ row_ptr, const int* __restrict__ col,
                               const float* __restrict__ rdeg, int N) {
  int g = blockIdx.x * blockDim.x + threadIdx.x;
  int node = g >> 1, h = (g & 1) * 4;
  if (node >= N) return;
  int j0 = row_ptr[node], j1 = row_ptr[node + 1];
  float4 acc = make_float4(0.f, 0.f, 0.f, 0.f);
  int j = j0;
  for (; j + 4 <= j1; j += 4) {
    float4 v0 = *(const float4*)&mesh[col[j] * 8 + h];
    float4 v1 = *(const float4*)&mesh[col[j + 1] * 8 + h];
    float4 v2 = *(const float4*)&mesh[col[j + 2] * 8 + h];
    float4 v3 = *(const float4*)&mesh[col[j + 3] * 8 + h];
    acc.x += (v0.x + v1.x) + (v2.x + v3.x);
    acc.y += (v0.y + v1.y) + (v2.y + v3.y);
    acc.z += (v0.z + v1.z) + (v2.z + v3.z);
    acc.w += (v0.w + v1.w) + (v2.w + v3.w);
  }
  for (; j < j1; ++j) {
    float4 v0 = *(const float4*)&mesh[col[j] * 8 + h];
    acc.x += v0.x; acc.y += v0.y; acc.z += v0.z; acc.w += v0.w;
  }
  float r = rdeg[node];
  acc.x *= r; acc.y *= r; acc.z *= r; acc.w *= r;
  *(float4*)&aggm[node * 8 + h] = acc;
}

// mterm[n][o] = bl[o] + sum_k Wl[o][4+k]*aggm[n][k] + Wr[o][4+k]*mesh[n][k]
__global__ void mesh_term_kernel(const float* __restrict__ aggm, const float* __restrict__ mesh,
                                 const float* __restrict__ Wl, const float* __restrict__ Wr,
                                 const float* __restrict__ bl, unsigned short* __restrict__ mterm,
                                 int N) {
  int g = blockIdx.x * blockDim.x + threadIdx.x;
  if (g >= N * 128) return;
  int n = g >> 7, o = g & 127;
  float acc = bl[o];
#pragma unroll
  for (int k = 0; k < 8; ++k)
    acc += Wl[o * 12 + 4 + k] * aggm[n * 8 + k] + Wr[o * 12 + 4 + k] * mesh[n * 8 + k];
  mterm[g] = f2bf(acc);
}

// ---------------- per-timestep kernels ----------------

// enc1: gather xprev (float4 rows), K=8 GEMM, + mterm, relu -> bf16.
__global__ __launch_bounds__(256) void enc1_kernel(
    const float* __restrict__ xprev, const int* __restrict__ row_ptr,
    const int* __restrict__ col, const float* __restrict__ rdeg,
    const float* __restrict__ Wl, const float* __restrict__ Wr,
    const unsigned short* __restrict__ mterm, unsigned short* __restrict__ out, int N) {
  __shared__ float Wx[8][128];   // k<4: Wl[:, k]; k>=4: Wr[:, k-4]
  __shared__ float4 part[256];
  __shared__ float As[64][8];    // [node][aggx(4) | own(4)]
  int tid = threadIdx.x;
  int nb = blockIdx.x * 64;
  for (int i = tid; i < 1024; i += 256) {
    int k = i >> 7, o = i & 127;
    Wx[k][o] = (k < 4) ? Wl[o * 12 + k] : Wr[o * 12 + (k - 4)];
  }
  int nl = tid >> 2, q = tid & 3;
  int gn = nb + nl; if (gn > N - 1) gn = N - 1;
  int j0 = row_ptr[gn], j1 = row_ptr[gn + 1];
  int per = (j1 - j0 + 3) >> 2;
  int a = j0 + q * per; if (a > j1) a = j1;
  int b = a + per; if (b > j1) b = j1;
  float4 acc = make_float4(0.f, 0.f, 0.f, 0.f);
  int j = a;
  for (; j + 2 <= b; j += 2) {
    float4 v0 = *(const float4*)&xprev[col[j] * 4];
    float4 v1 = *(const float4*)&xprev[col[j + 1] * 4];
    acc.x += v0.x + v1.x; acc.y += v0.y + v1.y;
    acc.z += v0.z + v1.z; acc.w += v0.w + v1.w;
  }
  if (j < b) {
    float4 v0 = *(const float4*)&xprev[col[j] * 4];
    acc.x += v0.x; acc.y += v0.y; acc.z += v0.z; acc.w += v0.w;
  }
  part[tid] = acc;
  __syncthreads();
  if (tid < 64) {
    int g2 = nb + tid; if (g2 > N - 1) g2 = N - 1;
    float4 s0 = part[tid * 4], s1 = part[tid * 4 + 1];
    float4 s2 = part[tid * 4 + 2], s3 = part[tid * 4 + 3];
    float r = rdeg[g2];
    As[tid][0] = (s0.x + s1.x + s2.x + s3.x) * r;
    As[tid][1] = (s0.y + s1.y + s2.y + s3.y) * r;
    As[tid][2] = (s0.z + s1.z + s2.z + s3.z) * r;
    As[tid][3] = (s0.w + s1.w + s2.w + s3.w) * r;
    float4 own = *(const float4*)&xprev[g2 * 4];
    As[tid][4] = own.x; As[tid][5] = own.y; As[tid][6] = own.z; As[tid][7] = own.w;
  }
  __syncthreads();
  int gn2 = nb + nl;
  if (gn2 >= N) return;
  float av[8];
#pragma unroll
  for (int k = 0; k < 8; ++k) av[k] = As[nl][k];
  int o0 = q * 32;
#pragma unroll
  for (int c = 0; c < 4; ++c) {
    ushort8 mt = *(const ushort8*)&mterm[gn2 * 128 + o0 + c * 8];
    ushort8 ov;
#pragma unroll
    for (int oo = 0; oo < 8; ++oo) {
      int o = o0 + c * 8 + oo;
      float s = b2f(mt[oo]);
#pragma unroll
      for (int k = 0; k < 8; ++k) s += av[k] * Wx[k][o];
      ov[oo] = f2bf(fmaxf(s, 0.0f));
    }
    *(ushort8*)&out[gn2 * 128 + o0 + c * 8] = ov;
  }
}

// bf16 mean-aggregate: 16 lanes/node, ushort8/lane, unroll-8 (R4 hot path)
__global__ void agg128_kernel(const unsigned short* __restrict__ feat,
                              unsigned short* __restrict__ out,
                              const int* __restrict__ row_ptr, const int* __restrict__ col,
                              const float* __restrict__ rdeg, int N) {
  int g = blockIdx.x * blockDim.x + threadIdx.x;
  int node = g >> 4;
  int d = g & 15;
  if (node >= N) return;
  int j0 = row_ptr[node], j1 = row_ptr[node + 1];
  float acc[8] = {};
  int j = j0;
  for (; j + 8 <= j1; j += 8) {
    ushort8 v0 = *(const ushort8*)&feat[col[j    ] * 128 + d * 8];
    ushort8 v1 = *(const ushort8*)&feat[col[j + 1] * 128 + d * 8];
    ushort8 v2 = *(const ushort8*)&feat[col[j + 2] * 128 + d * 8];
    ushort8 v3 = *(const ushort8*)&feat[col[j + 3] * 128 + d * 8];
    ushort8 v4 = *(const ushort8*)&feat[col[j + 4] * 128 + d * 8];
    ushort8 v5 = *(const ushort8*)&feat[col[j + 5] * 128 + d * 8];
    ushort8 v6 = *(const ushort8*)&feat[col[j + 6] * 128 + d * 8];
    ushort8 v7 = *(const ushort8*)&feat[col[j + 7] * 128 + d * 8];
#pragma unroll
    for (int r = 0; r < 8; ++r)
      acc[r] += ((b2f(v0[r]) + b2f(v1[r])) + (b2f(v2[r]) + b2f(v3[r]))) +
                ((b2f(v4[r]) + b2f(v5[r])) + (b2f(v6[r]) + b2f(v7[r])));
  }
  for (; j + 2 <= j1; j += 2) {
    ushort8 v0 = *(const ushort8*)&feat[col[j] * 128 + d * 8];
    ushort8 v1 = *(const ushort8*)&feat[col[j + 1] * 128 + d * 8];
#pragma unroll
    for (int r = 0; r < 8; ++r) acc[r] += b2f(v0[r]) + b2f(v1[r]);
  }
  if (j < j1) {
    ushort8 v0 = *(const ushort8*)&feat[col[j] * 128 + d * 8];
#pragma unroll
    for (int r = 0; r < 8; ++r) acc[r] += b2f(v0[r]);
  }
  float rd = rdeg[node];
  ushort8 o;
#pragma unroll
  for (int r = 0; r < 8; ++r) o[r] = f2bf(acc[r] * rd);
  *(ushort8*)&out[node * 128 + d * 8] = o;
}

// conv GEMM via MFMA: out = relu([agg|x] @ [Wl;Wr]^T + bl), bf16 in/out.
// 256 threads = 4 waves x 64 nodes each (block = 256 nodes): B-weight reads
// amortized over 2x more A-rows than R4 (GEMM is B-traffic-bound per R8).
__global__ __launch_bounds__(256) void gemm128_mfma_kernel(
    const unsigned short* __restrict__ agg, const unsigned short* __restrict__ x,
    const unsigned short* __restrict__ Wlb, const unsigned short* __restrict__ Wrb,
    const float* __restrict__ bl, unsigned short* __restrict__ out, int N) {
  int tid = threadIdx.x;
  int wave = tid >> 6;
  int lane = tid & 63;
  int nb = blockIdx.x * 256 + wave * 64;
  int l15 = lane & 15;
  int lk = (lane >> 4) * 8;

  f32x4 acc[4][8] = {};
  int r0 = nb + l15;      if (r0 > N - 1) r0 = N - 1;
  int r1 = nb + 16 + l15; if (r1 > N - 1) r1 = N - 1;
  int r2 = nb + 32 + l15; if (r2 > N - 1) r2 = N - 1;
  int r3 = nb + 48 + l15; if (r3 > N - 1) r3 = N - 1;

#pragma unroll
  for (int ks = 0; ks < 8; ++ks) {
    const unsigned short* As = (ks < 4) ? agg : x;
    const unsigned short* Ws = (ks < 4) ? Wlb : Wrb;
    int ko = (ks & 3) * 32 + lk;
    short8 a0 = *(const short8*)&As[r0 * 128 + ko];
    short8 a1 = *(const short8*)&As[r1 * 128 + ko];
    short8 a2 = *(const short8*)&As[r2 * 128 + ko];
    short8 a3 = *(const short8*)&As[r3 * 128 + ko];
#pragma unroll
    for (int ot = 0; ot < 8; ++ot) {
      short8 b = *(const short8*)&Ws[(ot * 16 + l15) * 128 + ko];
      acc[0][ot] = __builtin_amdgcn_mfma_f32_16x16x32_bf16(a0, b, acc[0][ot], 0, 0, 0);
      acc[1][ot] = __builtin_amdgcn_mfma_f32_16x16x32_bf16(a1, b, acc[1][ot], 0, 0, 0);
      acc[2][ot] = __builtin_amdgcn_mfma_f32_16x16x32_bf16(a2, b, acc[2][ot], 0, 0, 0);
      acc[3][ot] = __builtin_amdgcn_mfma_f32_16x16x32_bf16(a3, b, acc[3][ot], 0, 0, 0);
    }
  }

  int crow = (lane >> 4) * 4;   // C: col = lane&15, row = (lane>>4)*4 + reg
#pragma unroll
  for (int ot = 0; ot < 8; ++ot) {
    int gcol = ot * 16 + l15;
    float bv = bl[gcol];
#pragma unroll
    for (int mt = 0; mt < 4; ++mt) {
#pragma unroll
      for (int r = 0; r < 4; ++r) {
        int grow = nb + mt * 16 + crow + r;
        if (grow < N) {
          float v = fmaxf(acc[mt][ot][r] + bv, 0.0f);
          out[grow * 128 + gcol] = f2bf(v);
        }
      }
    }
  }
}

// dec2 GEMM + fused head (R4 exact): h = relu([agg|x]@[Wl;Wr]^T + bl);
// x_new = xprev + h@linW^T + linb; writes out[:,t,:] and xprev.
__global__ __launch_bounds__(256) void gemm128_head_mfma_kernel(
    const unsigned short* __restrict__ agg, const unsigned short* __restrict__ x,
    const unsigned short* __restrict__ Wlb, const unsigned short* __restrict__ Wrb,
    const float* __restrict__ bl, const float* __restrict__ linW,
    const float* __restrict__ linb, float* __restrict__ xprev,
    float* __restrict__ out, int N, int T, int t) {
  __shared__ float Wh[4][128];
  int tid = threadIdx.x;
  for (int i = tid; i < 512; i += 256) Wh[i >> 7][i & 127] = linW[i];
  __syncthreads();

  int wave = tid >> 6;
  int lane = tid & 63;
  int nb = blockIdx.x * 128 + wave * 32;
  int l15 = lane & 15;
  int lk = (lane >> 4) * 8;

  f32x4 acc[2][8] = {};
  int r0 = nb + l15;      if (r0 > N - 1) r0 = N - 1;
  int r1 = nb + 16 + l15; if (r1 > N - 1) r1 = N - 1;

#pragma unroll
  for (int ks = 0; ks < 8; ++ks) {
    const unsigned short* As = (ks < 4) ? agg : x;
    const unsigned short* Ws = (ks < 4) ? Wlb : Wrb;
    int ko = (ks & 3) * 32 + lk;
    short8 a0 = *(const short8*)&As[r0 * 128 + ko];
    short8 a1 = *(const short8*)&As[r1 * 128 + ko];
#pragma unroll
    for (int ot = 0; ot < 8; ++ot) {
      short8 b = *(const short8*)&Ws[(ot * 16 + l15) * 128 + ko];
      acc[0][ot] = __builtin_amdgcn_mfma_f32_16x16x32_bf16(a0, b, acc[0][ot], 0, 0, 0);
      acc[1][ot] = __builtin_amdgcn_mfma_f32_16x16x32_bf16(a1, b, acc[1][ot], 0, 0, 0);
    }
  }

  float part[2][4][4] = {};
#pragma unroll
  for (int ot = 0; ot < 8; ++ot) {
    int gcol = ot * 16 + l15;
    float bv = bl[gcol];
    float w0 = Wh[0][gcol], w1 = Wh[1][gcol], w2 = Wh[2][gcol], w3 = Wh[3][gcol];
#pragma unroll
    for (int mt = 0; mt < 2; ++mt)
#pragma unroll
      for (int r = 0; r < 4; ++r) {
        float hv = fmaxf(acc[mt][ot][r] + bv, 0.0f);
        part[mt][r][0] += hv * w0;
        part[mt][r][1] += hv * w1;
        part[mt][r][2] += hv * w2;
        part[mt][r][3] += hv * w3;
      }
  }
#pragma unroll
  for (int m = 1; m < 16; m <<= 1)
#pragma unroll
    for (int mt = 0; mt < 2; ++mt)
#pragma unroll
      for (int r = 0; r < 4; ++r)
#pragma unroll
        for (int o = 0; o < 4; ++o)
          part[mt][r][o] += __shfl_xor(part[mt][r][o], m, 64);

  if (l15 == 0) {
    int crow = (lane >> 4) * 4;
    float4 lb = *(const float4*)linb;
#pragma unroll
    for (int mt = 0; mt < 2; ++mt)
#pragma unroll
      for (int r = 0; r < 4; ++r) {
        int grow = nb + mt * 16 + crow + r;
        if (grow < N) {
          float4 xp = *(const float4*)&xprev[grow * 4];
          float4 xn;
          xn.x = xp.x + part[mt][r][0] + lb.x;
          xn.y = xp.y + part[mt][r][1] + lb.y;
          xn.z = xp.z + part[mt][r][2] + lb.z;
          xn.w = xp.w + part[mt][r][3] + lb.w;
          *(float4*)&out[(grow * T + t) * 4] = xn;
          *(float4*)&xprev[grow * 4] = xn;
        }
      }
  }
}

extern "C" void kernel_launch(void* const* d_in, const int* in_sizes, int n_in,
                              void* d_out, int out_size, void* d_ws, size_t ws_size,
                              hipStream_t stream) {
  const float* F0   = (const float*)d_in[0];
  const float* mesh = (const float*)d_in[1];
  const int*   eidx = (const int*)d_in[2];
  const float* e1Wl = (const float*)d_in[4];
  const float* e1bl = (const float*)d_in[5];
  const float* e1Wr = (const float*)d_in[6];
  const float* e2Wl = (const float*)d_in[7];
  const float* e2bl = (const float*)d_in[8];
  const float* e2Wr = (const float*)d_in[9];
  const float* d1Wl = (const float*)d_in[10];
  const float* d1bl = (const float*)d_in[11];
  const float* d1Wr = (const float*)d_in[12];
  const float* d2Wl = (const float*)d_in[13];
  const float* d2bl = (const float*)d_in[14];
  const float* d2Wr = (const float*)d_in[15];
  const float* linW = (const float*)d_in[16];
  const float* linb = (const float*)d_in[17];

  const int N = in_sizes[0] / 4;
  const int E = in_sizes[2] / 2;
  const int T = out_size / (N * 4);
  const int* src = eidx;
  const int* dst = eidx + E;

  size_t off = 0;
  auto alloc = [&](size_t bytes) -> void* {
    void* p = (char*)d_ws + off;
    off += (bytes + 511) & ~(size_t)511;
    return p;
  };
  int*   cnt     = (int*)alloc((size_t)N * 4);
  int*   row_ptr = (int*)alloc((size_t)(N + 1) * 4);
  int*   rank    = (int*)alloc((size_t)E * 4);
  int*   col     = (int*)alloc((size_t)E * 4);
  float* rdeg    = (float*)alloc((size_t)N * 4);
  float* xprev   = (float*)alloc((size_t)N * 4 * 4);
  float* aggm    = (float*)alloc((size_t)N * 8 * 4);
  int*   bsum    = (int*)alloc(256 * 4);
  int*   boff    = (int*)alloc(256 * 4);
  unsigned short* mterm = (unsigned short*)alloc((size_t)N * 128 * 2);
  unsigned short* h1   = (unsigned short*)alloc((size_t)N * 128 * 2);
  unsigned short* h2   = (unsigned short*)alloc((size_t)N * 128 * 2);
  unsigned short* aggb = (unsigned short*)alloc((size_t)N * 128 * 2);
  unsigned short* wb   = (unsigned short*)alloc((size_t)6 * 128 * 128 * 2);
  unsigned short* e2Wlb = wb + 0 * 16384;
  unsigned short* e2Wrb = wb + 1 * 16384;
  unsigned short* d1Wlb = wb + 2 * 16384;
  unsigned short* d1Wrb = wb + 3 * 16384;
  unsigned short* d2Wlb = wb + 4 * 16384;
  unsigned short* d2Wrb = wb + 5 * 16384;

  float* outp = (float*)d_out;

  const int NB = (N + 255) / 256;   // 196 <= 256

  // ---- once per launch: CSR + invariants ----
  hipMemsetAsync(cnt, 0, (size_t)N * 4, stream);
  count_rank_kernel<<<(E + 255) / 256, 256, 0, stream>>>(dst, cnt, rank, E);
  blocksum_kernel<<<NB, 256, 0, stream>>>(cnt, bsum, N);
  scan_sums_kernel<<<1, 256, 0, stream>>>(bsum, boff, NB);
  expand_kernel<<<NB, 256, 0, stream>>>(cnt, boff, row_ptr, rdeg, N);
  fill_csr2_kernel<<<(E + 255) / 256, 256, 0, stream>>>(src, dst, rank, row_ptr, col, E);
  f2bf6_kernel<<<(6 * 16384 + 255) / 256, 256, 0, stream>>>(
      e2Wl, e2Wr, d1Wl, d1Wr, d2Wl, d2Wr, wb);
  aggmesh_kernel<<<(N * 2 + 255) / 256, 256, 0, stream>>>(mesh, aggm, row_ptr, col, rdeg, N);
  mesh_term_kernel<<<(N * 128 + 255) / 256, 256, 0, stream>>>(aggm, mesh, e1Wl, e1Wr, e1bl,
                                                              mterm, N);
  hipMemcpyAsync(xprev, F0, (size_t)N * 4 * 4, hipMemcpyDeviceToDevice, stream);

  const int gAgg   = (N * 16 + 255) / 256;
  const int gGemm  = (N + 255) / 256;   // 256 nodes/block
  const int gHead  = (N + 127) / 128;   // 128 nodes/block (R4 exact)
  const int gEnc1  = (N + 63) / 64;

  for (int t = 0; t < T; ++t) {
    enc1_kernel<<<gEnc1, 256, 0, stream>>>(xprev, row_ptr, col, rdeg,
                                           e1Wl, e1Wr, mterm, h1, N);

    agg128_kernel<<<gAgg, 256, 0, stream>>>(h1, aggb, row_ptr, col, rdeg, N);
    gemm128_mfma_kernel<<<gGemm, 256, 0, stream>>>(aggb, h1, e2Wlb, e2Wrb, e2bl, h2, N);

    agg128_kernel<<<gAgg, 256, 0, stream>>>(h2, aggb, row_ptr, col, rdeg, N);
    gemm128_mfma_kernel<<<gGemm, 256, 0, stream>>>(aggb, h2, d1Wlb, d1Wrb, d1bl, h1, N);

    agg128_kernel<<<gAgg, 256, 0, stream>>>(h1, aggb, row_ptr, col, rdeg, N);
    gemm128_head_mfma_kernel<<<gHead, 256, 0, stream>>>(aggb, h1, d2Wlb, d2Wrb, d2bl,
                                                        linW, linb, xprev, outp, N, T, t);
  }
}

// Round 10
// 1640.627 us; speedup vs baseline: 1.1956x; 1.0623x over previous
//
#include <hip/hip_runtime.h>

// ---------------------------------------------------------------------------
// Recurrent GraphSAGE net. Round 10 = exact revert to R4 (empirical optimum,
// 1642 us). All six subsequent single-variable experiments regressed or were
// null; see session journal. Structure:
//  - mesh contribution of enc1 precomputed once per launch (timestep-invariant)
//  - agg128: 16 lanes/node, ushort8 loads, unroll-8, max-TLP grid
//  - MFMA conv GEMMs: 4 waves x 32 nodes, 128-node blocks, 391-block grid
//  - dec2 GEMM + head fused (in-register 16-lane reduce)
//  - CSR built once per launch, no atomics on the fill
// Per timestep: enc1, [agg, gemm] x2, [agg, gemm+head] = 7 dispatches.
// ---------------------------------------------------------------------------

typedef __attribute__((ext_vector_type(8))) short short8;
typedef __attribute__((ext_vector_type(8))) unsigned short ushort8;
typedef __attribute__((ext_vector_type(4))) float f32x4;

static __device__ __forceinline__ float b2f(unsigned short u) {
  return __uint_as_float(((unsigned int)u) << 16);
}
static __device__ __forceinline__ unsigned short f2bf(float f) {
  unsigned int u = __float_as_uint(f);
  u += 0x7FFFu + ((u >> 16) & 1u);   // round-nearest-even
  return (unsigned short)(u >> 16);
}

// ---------------- graph preprocessing ----------------

__global__ void count_rank_kernel(const int* __restrict__ dst, int* __restrict__ cnt,
                                  int* __restrict__ rank, int E) {
  int e = blockIdx.x * blockDim.x + threadIdx.x;
  if (e < E) rank[e] = atomicAdd(&cnt[dst[e]], 1);
}

__global__ __launch_bounds__(256) void blocksum_kernel(const int* __restrict__ cnt,
                                                       int* __restrict__ bsum, int n) {
  __shared__ int s[256];
  int tid = threadIdx.x;
  int i = blockIdx.x * 256 + tid;
  s[tid] = (i < n) ? cnt[i] : 0;
  __syncthreads();
  for (int off = 128; off > 0; off >>= 1) {
    if (tid < off) s[tid] += s[tid + off];
    __syncthreads();
  }
  if (tid == 0) bsum[blockIdx.x] = s[0];
}

__global__ __launch_bounds__(256) void scan_sums_kernel(const int* __restrict__ bsum,
                                                        int* __restrict__ boff, int nb) {
  __shared__ int s[256];
  int tid = threadIdx.x;
  int v = (tid < nb) ? bsum[tid] : 0;
  s[tid] = v;
  __syncthreads();
  for (int off = 1; off < 256; off <<= 1) {
    int t = (tid >= off) ? s[tid - off] : 0;
    __syncthreads();
    s[tid] += t;
    __syncthreads();
  }
  if (tid < nb) boff[tid] = s[tid] - v;   // exclusive
}

__global__ __launch_bounds__(256) void expand_kernel(const int* __restrict__ cnt,
                                                     const int* __restrict__ boff,
                                                     int* __restrict__ row_ptr,
                                                     float* __restrict__ rdeg, int n) {
  __shared__ int s[256];
  int tid = threadIdx.x;
  int i = blockIdx.x * 256 + tid;
  int v = (i < n) ? cnt[i] : 0;
  s[tid] = v;
  __syncthreads();
  for (int off = 1; off < 256; off <<= 1) {
    int t = (tid >= off) ? s[tid - off] : 0;
    __syncthreads();
    s[tid] += t;
    __syncthreads();
  }
  if (i < n) {
    row_ptr[i + 1] = boff[blockIdx.x] + s[tid];
    rdeg[i] = 1.0f / fmaxf((float)v, 1.0f);
  }
  if (i == 0) row_ptr[0] = 0;
}

// no atomics: slot position = row_ptr[dst] + rank (recorded during count)
__global__ void fill_csr2_kernel(const int* __restrict__ src, const int* __restrict__ dst,
                                 const int* __restrict__ rank, const int* __restrict__ row_ptr,
                                 int* __restrict__ col, int E) {
  int e = blockIdx.x * blockDim.x + threadIdx.x;
  if (e < E) col[row_ptr[dst[e]] + rank[e]] = src[e];
}

// convert all 6 conv weight matrices (128x128 each) in one dispatch
__global__ void f2bf6_kernel(const float* __restrict__ s0, const float* __restrict__ s1,
                             const float* __restrict__ s2, const float* __restrict__ s3,
                             const float* __restrict__ s4, const float* __restrict__ s5,
                             unsigned short* __restrict__ dst) {
  int i = blockIdx.x * blockDim.x + threadIdx.x;
  if (i >= 6 * 16384) return;
  int m = i >> 14, o = i & 16383;
  const float* s;
  switch (m) {
    case 0: s = s0; break; case 1: s = s1; break; case 2: s = s2; break;
    case 3: s = s3; break; case 4: s = s4; break; default: s = s5; break;
  }
  dst[i] = f2bf(s[o]);
}

// mean-aggregate mesh (8 fp32 ch): 2 lanes/node, float4/lane, once per launch
__global__ void aggmesh_kernel(const float* __restrict__ mesh, float* __restrict__ aggm,
                               const int* __restrict__ row_ptr, const int* __restrict__ col,
                               const float* __restrict__ rdeg, int N) {
  int g = blockIdx.x * blockDim.x + threadIdx.x;
  int node = g >> 1, h = (g & 1) * 4;
  if (node >= N) return;
  int j0 = row_ptr[node], j1 = row_ptr[node + 1];
  float4 acc = make_float4(0.f, 0.f, 0.f, 0.f);
  int j = j0;
  for (; j + 4 <= j1; j += 4) {
    float4 v0 = *(const float4*)&mesh[col[j] * 8 + h];
    float4 v1 = *(const float4*)&mesh[col[j + 1] * 8 + h];
    float4 v2 = *(const float4*)&mesh[col[j + 2] * 8 + h];
    float4 v3 = *(const float4*)&mesh[col[j + 3] * 8 + h];
    acc.x += (v0.x + v1.x) + (v2.x + v3.x);
    acc.y += (v0.y + v1.y) + (v2.y + v3.y);
    acc.z += (v0.z + v1.z) + (v2.z + v3.z);
    acc.w += (v0.w + v1.w) + (v2.w + v3.w);
  }
  for (; j < j1; ++j) {
    float4 v0 = *(const float4*)&mesh[col[j] * 8 + h];
    acc.x += v0.x; acc.y += v0.y; acc.z += v0.z; acc.w += v0.w;
  }
  float r = rdeg[node];
  acc.x *= r; acc.y *= r; acc.z *= r; acc.w *= r;
  *(float4*)&aggm[node * 8 + h] = acc;
}

// mterm[n][o] = bl[o] + sum_k Wl[o][4+k]*aggm[n][k] + Wr[o][4+k]*mesh[n][k]
__global__ void mesh_term_kernel(const float* __restrict__ aggm, const float* __restrict__ mesh,
                                 const float* __restrict__ Wl, const float* __restrict__ Wr,
                                 const float* __restrict__ bl, unsigned short* __restrict__ mterm,
                                 int N) {
  int g = blockIdx.x * blockDim.x + threadIdx.x;
  if (g >= N * 128) return;
  int n = g >> 7, o = g & 127;
  float acc = bl[o];
#pragma unroll
  for (int k = 0; k < 8; ++k)
    acc += Wl[o * 12 + 4 + k] * aggm[n * 8 + k] + Wr[o * 12 + 4 + k] * mesh[n * 8 + k];
  mterm[g] = f2bf(acc);
}

// ---------------- per-timestep kernels ----------------

// enc1: gather xprev (float4 rows), K=8 GEMM, + mterm, relu -> bf16.
// 64 nodes/block; 4 threads per node for the gather; thread -> 32 outputs.
__global__ __launch_bounds__(256) void enc1_kernel(
    const float* __restrict__ xprev, const int* __restrict__ row_ptr,
    const int* __restrict__ col, const float* __restrict__ rdeg,
    const float* __restrict__ Wl, const float* __restrict__ Wr,
    const unsigned short* __restrict__ mterm, unsigned short* __restrict__ out, int N) {
  __shared__ float Wx[8][128];   // k<4: Wl[:, k]; k>=4: Wr[:, k-4]
  __shared__ float4 part[256];
  __shared__ float As[64][8];    // [node][aggx(4) | own(4)]
  int tid = threadIdx.x;
  int nb = blockIdx.x * 64;
  for (int i = tid; i < 1024; i += 256) {
    int k = i >> 7, o = i & 127;
    Wx[k][o] = (k < 4) ? Wl[o * 12 + k] : Wr[o * 12 + (k - 4)];
  }
  int nl = tid >> 2, q = tid & 3;
  int gn = nb + nl; if (gn > N - 1) gn = N - 1;
  int j0 = row_ptr[gn], j1 = row_ptr[gn + 1];
  int per = (j1 - j0 + 3) >> 2;
  int a = j0 + q * per; if (a > j1) a = j1;
  int b = a + per; if (b > j1) b = j1;
  float4 acc = make_float4(0.f, 0.f, 0.f, 0.f);
  int j = a;
  for (; j + 2 <= b; j += 2) {
    float4 v0 = *(const float4*)&xprev[col[j] * 4];
    float4 v1 = *(const float4*)&xprev[col[j + 1] * 4];
    acc.x += v0.x + v1.x; acc.y += v0.y + v1.y;
    acc.z += v0.z + v1.z; acc.w += v0.w + v1.w;
  }
  if (j < b) {
    float4 v0 = *(const float4*)&xprev[col[j] * 4];
    acc.x += v0.x; acc.y += v0.y; acc.z += v0.z; acc.w += v0.w;
  }
  part[tid] = acc;
  __syncthreads();
  if (tid < 64) {
    int g2 = nb + tid; if (g2 > N - 1) g2 = N - 1;
    float4 s0 = part[tid * 4], s1 = part[tid * 4 + 1];
    float4 s2 = part[tid * 4 + 2], s3 = part[tid * 4 + 3];
    float r = rdeg[g2];
    As[tid][0] = (s0.x + s1.x + s2.x + s3.x) * r;
    As[tid][1] = (s0.y + s1.y + s2.y + s3.y) * r;
    As[tid][2] = (s0.z + s1.z + s2.z + s3.z) * r;
    As[tid][3] = (s0.w + s1.w + s2.w + s3.w) * r;
    float4 own = *(const float4*)&xprev[g2 * 4];
    As[tid][4] = own.x; As[tid][5] = own.y; As[tid][6] = own.z; As[tid][7] = own.w;
  }
  __syncthreads();
  int gn2 = nb + nl;
  if (gn2 >= N) return;
  float av[8];
#pragma unroll
  for (int k = 0; k < 8; ++k) av[k] = As[nl][k];
  int o0 = q * 32;
#pragma unroll
  for (int c = 0; c < 4; ++c) {
    ushort8 mt = *(const ushort8*)&mterm[gn2 * 128 + o0 + c * 8];
    ushort8 ov;
#pragma unroll
    for (int oo = 0; oo < 8; ++oo) {
      int o = o0 + c * 8 + oo;
      float s = b2f(mt[oo]);
#pragma unroll
      for (int k = 0; k < 8; ++k) s += av[k] * Wx[k][o];
      ov[oo] = f2bf(fmaxf(s, 0.0f));
    }
    *(ushort8*)&out[gn2 * 128 + o0 + c * 8] = ov;
  }
}

// bf16 mean-aggregate: 16 lanes/node, ushort8/lane, unroll-8 (8 loads in flight)
__global__ void agg128_kernel(const unsigned short* __restrict__ feat,
                              unsigned short* __restrict__ out,
                              const int* __restrict__ row_ptr, const int* __restrict__ col,
                              const float* __restrict__ rdeg, int N) {
  int g = blockIdx.x * blockDim.x + threadIdx.x;
  int node = g >> 4;
  int d = g & 15;
  if (node >= N) return;
  int j0 = row_ptr[node], j1 = row_ptr[node + 1];
  float acc[8] = {};
  int j = j0;
  for (; j + 8 <= j1; j += 8) {
    ushort8 v0 = *(const ushort8*)&feat[col[j    ] * 128 + d * 8];
    ushort8 v1 = *(const ushort8*)&feat[col[j + 1] * 128 + d * 8];
    ushort8 v2 = *(const ushort8*)&feat[col[j + 2] * 128 + d * 8];
    ushort8 v3 = *(const ushort8*)&feat[col[j + 3] * 128 + d * 8];
    ushort8 v4 = *(const ushort8*)&feat[col[j + 4] * 128 + d * 8];
    ushort8 v5 = *(const ushort8*)&feat[col[j + 5] * 128 + d * 8];
    ushort8 v6 = *(const ushort8*)&feat[col[j + 6] * 128 + d * 8];
    ushort8 v7 = *(const ushort8*)&feat[col[j + 7] * 128 + d * 8];
#pragma unroll
    for (int r = 0; r < 8; ++r)
      acc[r] += ((b2f(v0[r]) + b2f(v1[r])) + (b2f(v2[r]) + b2f(v3[r]))) +
                ((b2f(v4[r]) + b2f(v5[r])) + (b2f(v6[r]) + b2f(v7[r])));
  }
  for (; j + 2 <= j1; j += 2) {
    ushort8 v0 = *(const ushort8*)&feat[col[j] * 128 + d * 8];
    ushort8 v1 = *(const ushort8*)&feat[col[j + 1] * 128 + d * 8];
#pragma unroll
    for (int r = 0; r < 8; ++r) acc[r] += b2f(v0[r]) + b2f(v1[r]);
  }
  if (j < j1) {
    ushort8 v0 = *(const ushort8*)&feat[col[j] * 128 + d * 8];
#pragma unroll
    for (int r = 0; r < 8; ++r) acc[r] += b2f(v0[r]);
  }
  float rd = rdeg[node];
  ushort8 o;
#pragma unroll
  for (int r = 0; r < 8; ++r) o[r] = f2bf(acc[r] * rd);
  *(ushort8*)&out[node * 128 + d * 8] = o;
}

// conv GEMM via MFMA: out = relu([agg|x] @ [Wl;Wr]^T + bl), bf16 in/out
__global__ __launch_bounds__(256) void gemm128_mfma_kernel(
    const unsigned short* __restrict__ agg, const unsigned short* __restrict__ x,
    const unsigned short* __restrict__ Wlb, const unsigned short* __restrict__ Wrb,
    const float* __restrict__ bl, unsigned short* __restrict__ out, int N) {
  int tid = threadIdx.x;
  int wave = tid >> 6;
  int lane = tid & 63;
  int nb = blockIdx.x * 128 + wave * 32;
  int l15 = lane & 15;
  int lk = (lane >> 4) * 8;

  f32x4 acc[2][8] = {};
  int r0 = nb + l15;      if (r0 > N - 1) r0 = N - 1;
  int r1 = nb + 16 + l15; if (r1 > N - 1) r1 = N - 1;

#pragma unroll
  for (int ks = 0; ks < 8; ++ks) {
    const unsigned short* As = (ks < 4) ? agg : x;
    const unsigned short* Ws = (ks < 4) ? Wlb : Wrb;
    int ko = (ks & 3) * 32 + lk;
    short8 a0 = *(const short8*)&As[r0 * 128 + ko];
    short8 a1 = *(const short8*)&As[r1 * 128 + ko];
#pragma unroll
    for (int ot = 0; ot < 8; ++ot) {
      short8 b = *(const short8*)&Ws[(ot * 16 + l15) * 128 + ko];
      acc[0][ot] = __builtin_amdgcn_mfma_f32_16x16x32_bf16(a0, b, acc[0][ot], 0, 0, 0);
      acc[1][ot] = __builtin_amdgcn_mfma_f32_16x16x32_bf16(a1, b, acc[1][ot], 0, 0, 0);
    }
  }

  int crow = (lane >> 4) * 4;   // C: col = lane&15, row = (lane>>4)*4 + reg
#pragma unroll
  for (int ot = 0; ot < 8; ++ot) {
    int gcol = ot * 16 + l15;
    float bv = bl[gcol];
#pragma unroll
    for (int mt = 0; mt < 2; ++mt) {
#pragma unroll
      for (int r = 0; r < 4; ++r) {
        int grow = nb + mt * 16 + crow + r;
        if (grow < N) {
          float v = fmaxf(acc[mt][ot][r] + bv, 0.0f);
          out[grow * 128 + gcol] = f2bf(v);
        }
      }
    }
  }
}

// dec2 GEMM + fused head: h = relu([agg|x]@[Wl;Wr]^T + bl);
// x_new = xprev + h@linW^T + linb; writes out[:,t,:] and xprev.
__global__ __launch_bounds__(256) void gemm128_head_mfma_kernel(
    const unsigned short* __restrict__ agg, const unsigned short* __restrict__ x,
    const unsigned short* __restrict__ Wlb, const unsigned short* __restrict__ Wrb,
    const float* __restrict__ bl, const float* __restrict__ linW,
    const float* __restrict__ linb, float* __restrict__ xprev,
    float* __restrict__ out, int N, int T, int t) {
  __shared__ float Wh[4][128];
  int tid = threadIdx.x;
  for (int i = tid; i < 512; i += 256) Wh[i >> 7][i & 127] = linW[i];
  __syncthreads();

  int wave = tid >> 6;
  int lane = tid & 63;
  int nb = blockIdx.x * 128 + wave * 32;
  int l15 = lane & 15;
  int lk = (lane >> 4) * 8;

  f32x4 acc[2][8] = {};
  int r0 = nb + l15;      if (r0 > N - 1) r0 = N - 1;
  int r1 = nb + 16 + l15; if (r1 > N - 1) r1 = N - 1;

#pragma unroll
  for (int ks = 0; ks < 8; ++ks) {
    const unsigned short* As = (ks < 4) ? agg : x;
    const unsigned short* Ws = (ks < 4) ? Wlb : Wrb;
    int ko = (ks & 3) * 32 + lk;
    short8 a0 = *(const short8*)&As[r0 * 128 + ko];
    short8 a1 = *(const short8*)&As[r1 * 128 + ko];
#pragma unroll
    for (int ot = 0; ot < 8; ++ot) {
      short8 b = *(const short8*)&Ws[(ot * 16 + l15) * 128 + ko];
      acc[0][ot] = __builtin_amdgcn_mfma_f32_16x16x32_bf16(a0, b, acc[0][ot], 0, 0, 0);
      acc[1][ot] = __builtin_amdgcn_mfma_f32_16x16x32_bf16(a1, b, acc[1][ot], 0, 0, 0);
    }
  }

  float part[2][4][4] = {};
#pragma unroll
  for (int ot = 0; ot < 8; ++ot) {
    int gcol = ot * 16 + l15;
    float bv = bl[gcol];
    float w0 = Wh[0][gcol], w1 = Wh[1][gcol], w2 = Wh[2][gcol], w3 = Wh[3][gcol];
#pragma unroll
    for (int mt = 0; mt < 2; ++mt)
#pragma unroll
      for (int r = 0; r < 4; ++r) {
        float hv = fmaxf(acc[mt][ot][r] + bv, 0.0f);
        part[mt][r][0] += hv * w0;
        part[mt][r][1] += hv * w1;
        part[mt][r][2] += hv * w2;
        part[mt][r][3] += hv * w3;
      }
  }
#pragma unroll
  for (int m = 1; m < 16; m <<= 1)
#pragma unroll
    for (int mt = 0; mt < 2; ++mt)
#pragma unroll
      for (int r = 0; r < 4; ++r)
#pragma unroll
        for (int o = 0; o < 4; ++o)
          part[mt][r][o] += __shfl_xor(part[mt][r][o], m, 64);

  if (l15 == 0) {
    int crow = (lane >> 4) * 4;
    float4 lb = *(const float4*)linb;
#pragma unroll
    for (int mt = 0; mt < 2; ++mt)
#pragma unroll
      for (int r = 0; r < 4; ++r) {
        int grow = nb + mt * 16 + crow + r;
        if (grow < N) {
          float4 xp = *(const float4*)&xprev[grow * 4];
          float4 xn;
          xn.x = xp.x + part[mt][r][0] + lb.x;
          xn.y = xp.y + part[mt][r][1] + lb.y;
          xn.z = xp.z + part[mt][r][2] + lb.z;
          xn.w = xp.w + part[mt][r][3] + lb.w;
          *(float4*)&out[(grow * T + t) * 4] = xn;
          *(float4*)&xprev[grow * 4] = xn;
        }
      }
  }
}

extern "C" void kernel_launch(void* const* d_in, const int* in_sizes, int n_in,
                              void* d_out, int out_size, void* d_ws, size_t ws_size,
                              hipStream_t stream) {
  const float* F0   = (const float*)d_in[0];
  const float* mesh = (const float*)d_in[1];
  const int*   eidx = (const int*)d_in[2];
  const float* e1Wl = (const float*)d_in[4];
  const float* e1bl = (const float*)d_in[5];
  const float* e1Wr = (const float*)d_in[6];
  const float* e2Wl = (const float*)d_in[7];
  const float* e2bl = (const float*)d_in[8];
  const float* e2Wr = (const float*)d_in[9];
  const float* d1Wl = (const float*)d_in[10];
  const float* d1bl = (const float*)d_in[11];
  const float* d1Wr = (const float*)d_in[12];
  const float* d2Wl = (const float*)d_in[13];
  const float* d2bl = (const float*)d_in[14];
  const float* d2Wr = (const float*)d_in[15];
  const float* linW = (const float*)d_in[16];
  const float* linb = (const float*)d_in[17];

  const int N = in_sizes[0] / 4;
  const int E = in_sizes[2] / 2;
  const int T = out_size / (N * 4);
  const int* src = eidx;
  const int* dst = eidx + E;

  size_t off = 0;
  auto alloc = [&](size_t bytes) -> void* {
    void* p = (char*)d_ws + off;
    off += (bytes + 511) & ~(size_t)511;
    return p;
  };
  int*   cnt     = (int*)alloc((size_t)N * 4);
  int*   row_ptr = (int*)alloc((size_t)(N + 1) * 4);
  int*   rank    = (int*)alloc((size_t)E * 4);
  int*   col     = (int*)alloc((size_t)E * 4);
  float* rdeg    = (float*)alloc((size_t)N * 4);
  float* xprev   = (float*)alloc((size_t)N * 4 * 4);
  float* aggm    = (float*)alloc((size_t)N * 8 * 4);
  int*   bsum    = (int*)alloc(256 * 4);
  int*   boff    = (int*)alloc(256 * 4);
  unsigned short* mterm = (unsigned short*)alloc((size_t)N * 128 * 2);
  unsigned short* h1   = (unsigned short*)alloc((size_t)N * 128 * 2);
  unsigned short* h2   = (unsigned short*)alloc((size_t)N * 128 * 2);
  unsigned short* aggb = (unsigned short*)alloc((size_t)N * 128 * 2);
  unsigned short* wb   = (unsigned short*)alloc((size_t)6 * 128 * 128 * 2);
  unsigned short* e2Wlb = wb + 0 * 16384;
  unsigned short* e2Wrb = wb + 1 * 16384;
  unsigned short* d1Wlb = wb + 2 * 16384;
  unsigned short* d1Wrb = wb + 3 * 16384;
  unsigned short* d2Wlb = wb + 4 * 16384;
  unsigned short* d2Wrb = wb + 5 * 16384;

  float* outp = (float*)d_out;

  const int NB = (N + 255) / 256;   // 196 <= 256

  // ---- once per launch: CSR + invariants ----
  hipMemsetAsync(cnt, 0, (size_t)N * 4, stream);
  count_rank_kernel<<<(E + 255) / 256, 256, 0, stream>>>(dst, cnt, rank, E);
  blocksum_kernel<<<NB, 256, 0, stream>>>(cnt, bsum, N);
  scan_sums_kernel<<<1, 256, 0, stream>>>(bsum, boff, NB);
  expand_kernel<<<NB, 256, 0, stream>>>(cnt, boff, row_ptr, rdeg, N);
  fill_csr2_kernel<<<(E + 255) / 256, 256, 0, stream>>>(src, dst, rank, row_ptr, col, E);
  f2bf6_kernel<<<(6 * 16384 + 255) / 256, 256, 0, stream>>>(
      e2Wl, e2Wr, d1Wl, d1Wr, d2Wl, d2Wr, wb);
  aggmesh_kernel<<<(N * 2 + 255) / 256, 256, 0, stream>>>(mesh, aggm, row_ptr, col, rdeg, N);
  mesh_term_kernel<<<(N * 128 + 255) / 256, 256, 0, stream>>>(aggm, mesh, e1Wl, e1Wr, e1bl,
                                                              mterm, N);
  hipMemcpyAsync(xprev, F0, (size_t)N * 4 * 4, hipMemcpyDeviceToDevice, stream);

  const int gAgg  = (N * 16 + 255) / 256;
  const int gGemm = (N + 127) / 128;
  const int gEnc1 = (N + 63) / 64;

  for (int t = 0; t < T; ++t) {
    enc1_kernel<<<gEnc1, 256, 0, stream>>>(xprev, row_ptr, col, rdeg,
                                           e1Wl, e1Wr, mterm, h1, N);

    agg128_kernel<<<gAgg, 256, 0, stream>>>(h1, aggb, row_ptr, col, rdeg, N);
    gemm128_mfma_kernel<<<gGemm, 256, 0, stream>>>(aggb, h1, e2Wlb, e2Wrb, e2bl, h2, N);

    agg128_kernel<<<gAgg, 256, 0, stream>>>(h2, aggb, row_ptr, col, rdeg, N);
    gemm128_mfma_kernel<<<gGemm, 256, 0, stream>>>(aggb, h2, d1Wlb, d1Wrb, d1bl, h1, N);

    agg128_kernel<<<gAgg, 256, 0, stream>>>(h1, aggb, row_ptr, col, rdeg, N);
    gemm128_head_mfma_kernel<<<gGemm, 256, 0, stream>>>(aggb, h1, d2Wlb, d2Wrb, d2bl,
                                                        linW, linb, xprev, outp, N, T, t);
  }
}